// Round 2
// baseline (930.327 us; speedup 1.0000x reference)
//
#include <hip/hip_runtime.h>
#include <math.h>

#define D_MODEL 1024
#define NUM_HEADS 16
#define DK 64
#define L_SEQ 2048
#define BATCH 2
#define LN_EPS 1e-5f
#define ENERGY_SCALE 0.1f

typedef __attribute__((ext_vector_type(8))) short short8;
typedef __attribute__((ext_vector_type(4))) float f32x4;
typedef __attribute__((address_space(1))) const unsigned int gas_u32;
typedef __attribute__((address_space(3))) unsigned int las_u32;

__device__ __forceinline__ float waveReduceSum(float v) {
#pragma unroll
    for (int off = 32; off > 0; off >>= 1) v += __shfl_xor(v, off, 64);
    return v;
}

__device__ __forceinline__ unsigned short f2bf(float f) {
    unsigned int u = __float_as_uint(f);
    u += 0x7fff + ((u >> 16) & 1);          // round-to-nearest-even
    return (unsigned short)(u >> 16);
}
__device__ __forceinline__ float bf2f(unsigned short u) {
    return __uint_as_float((unsigned int)u << 16);
}

// ---------------- fp32 -> bf16 convert, 6 matrices in one launch ----------------
__global__ __launch_bounds__(256) void cvt6(
    const float* s0, const float* s1, const float* s2,
    const float* s3, const float* s4, const float* s5,
    unsigned short* d0, unsigned short* d1, unsigned short* d2,
    unsigned short* d3, unsigned short* d4, unsigned short* d5,
    long long n0, long long n1, long long n2, long long n3, long long n4, long long n5)
{
    const float* s; unsigned short* d; long long n;
    switch (blockIdx.y) {
        case 0: s = s0; d = d0; n = n0; break;
        case 1: s = s1; d = d1; n = n1; break;
        case 2: s = s2; d = d2; n = n2; break;
        case 3: s = s3; d = d3; n = n3; break;
        case 4: s = s4; d = d4; n = n4; break;
        default: s = s5; d = d5; n = n5; break;
    }
    long long i = ((long long)blockIdx.x * 256 + threadIdx.x) * 4;
    if (i >= n) return;
    float4 v = *(const float4*)(s + i);
    ushort4 o;
    o.x = f2bf(v.x); o.y = f2bf(v.y); o.z = f2bf(v.z); o.w = f2bf(v.w);
    *(ushort4*)(d + i) = o;
}

// ---------------- bf16 MFMA GEMM with global_load_lds (round-8 verified) ----------------
__global__ __launch_bounds__(256) void gemm_bf16(
    const unsigned short* __restrict__ A, const unsigned short* __restrict__ B,
    const float* __restrict__ bias, float* __restrict__ Cf, unsigned short* __restrict__ Ch,
    int N, int K, long long sA, long long sB, long long sC)
{
    A += (long long)blockIdx.z * sA;
    B += (long long)blockIdx.z * sB;
    __shared__ unsigned short As[128 * 64];
    __shared__ unsigned short Bs[128 * 64];
    const int tid = threadIdx.x;
    const int lane = tid & 63, w = tid >> 6;
    const int quad = lane >> 4, col = lane & 15;
    const int wm = w & 1, wn = w >> 1;
    const int row0 = blockIdx.y * 128, col0 = blockIdx.x * 128;

    const int lr = lane >> 3, lc = lane & 7;
    const int gcs = (lc ^ lr) * 8;

    f32x4 acc[4][4];
#pragma unroll
    for (int mt = 0; mt < 4; mt++)
#pragma unroll
        for (int nt = 0; nt < 4; nt++) acc[mt][nt] = (f32x4){0.f, 0.f, 0.f, 0.f};

    for (int k0 = 0; k0 < K; k0 += 64) {
        __syncthreads();
#pragma unroll
        for (int p = 0; p < 4; p++) {
            const int rb = w * 32 + p * 8;
            __builtin_amdgcn_global_load_lds(
                (gas_u32*)(A + (long long)(row0 + rb + lr) * K + k0 + gcs),
                (las_u32*)(As + rb * 64), 16, 0, 0);
            __builtin_amdgcn_global_load_lds(
                (gas_u32*)(B + (long long)(col0 + rb + lr) * K + k0 + gcs),
                (las_u32*)(Bs + rb * 64), 16, 0, 0);
        }
        __syncthreads();
#pragma unroll
        for (int kc = 0; kc < 2; kc++) {
            const int csw = ((quad + 4 * kc) ^ (col & 7)) * 8;
            short8 af[4], bfr[4];
#pragma unroll
            for (int mt = 0; mt < 4; mt++)
                af[mt] = *(const short8*)(As + (wm * 64 + mt * 16 + col) * 64 + csw);
#pragma unroll
            for (int nt = 0; nt < 4; nt++)
                bfr[nt] = *(const short8*)(Bs + (wn * 64 + nt * 16 + col) * 64 + csw);
#pragma unroll
            for (int mt = 0; mt < 4; mt++)
#pragma unroll
                for (int nt = 0; nt < 4; nt++)
                    acc[mt][nt] = __builtin_amdgcn_mfma_f32_16x16x32_bf16(af[mt], bfr[nt], acc[mt][nt], 0, 0, 0);
        }
    }

#pragma unroll
    for (int mt = 0; mt < 4; mt++)
#pragma unroll
        for (int nt = 0; nt < 4; nt++)
#pragma unroll
            for (int reg = 0; reg < 4; reg++) {
                long long row = row0 + wm * 64 + mt * 16 + quad * 4 + reg;
                int c = col0 + wn * 64 + nt * 16 + col;
                float v = acc[mt][nt][reg];
                if (bias) v += bias[c];
                if (Cf) Cf[blockIdx.z * sC + row * N + c] = v;
                else    Ch[blockIdx.z * sC + row * N + c] = f2bf(v);
            }
}

// ---------------- fused projections with global_load_lds (round-8 verified) ----------------
__global__ __launch_bounds__(256) void proj_gemm(
    const unsigned short* __restrict__ Xh,
    const unsigned short* __restrict__ wqh, const unsigned short* __restrict__ wkh,
    const unsigned short* __restrict__ wvh, const unsigned short* __restrict__ eph,
    const float* __restrict__ ep_b,
    unsigned short* __restrict__ Qh, unsigned short* __restrict__ Kh,
    unsigned short* __restrict__ Vf, float* __restrict__ EP)
{
    const unsigned short* B;
    switch (blockIdx.z) {
        case 0: B = wqh; break;
        case 1: B = wkh; break;
        case 2: B = wvh; break;
        default: B = eph; break;
    }
    __shared__ unsigned short As[128 * 64];
    __shared__ unsigned short Bs[128 * 64];
    const int tid = threadIdx.x;
    const int lane = tid & 63, w = tid >> 6;
    const int quad = lane >> 4, col = lane & 15;
    const int wm = w & 1, wn = w >> 1;
    const int row0 = blockIdx.y * 128, col0 = blockIdx.x * 128;
    const int K = D_MODEL, N = D_MODEL;

    const int lr = lane >> 3, lc = lane & 7;
    const int gcs = (lc ^ lr) * 8;

    f32x4 acc[4][4];
#pragma unroll
    for (int mt = 0; mt < 4; mt++)
#pragma unroll
        for (int nt = 0; nt < 4; nt++) acc[mt][nt] = (f32x4){0.f, 0.f, 0.f, 0.f};

    for (int k0 = 0; k0 < K; k0 += 64) {
        __syncthreads();
#pragma unroll
        for (int p = 0; p < 4; p++) {
            const int rb = w * 32 + p * 8;
            __builtin_amdgcn_global_load_lds(
                (gas_u32*)(Xh + (long long)(row0 + rb + lr) * K + k0 + gcs),
                (las_u32*)(As + rb * 64), 16, 0, 0);
            __builtin_amdgcn_global_load_lds(
                (gas_u32*)(B + (long long)(col0 + rb + lr) * K + k0 + gcs),
                (las_u32*)(Bs + rb * 64), 16, 0, 0);
        }
        __syncthreads();
#pragma unroll
        for (int kc = 0; kc < 2; kc++) {
            const int csw = ((quad + 4 * kc) ^ (col & 7)) * 8;
            short8 af[4], bfr[4];
#pragma unroll
            for (int mt = 0; mt < 4; mt++)
                af[mt] = *(const short8*)(As + (wm * 64 + mt * 16 + col) * 64 + csw);
#pragma unroll
            for (int nt = 0; nt < 4; nt++)
                bfr[nt] = *(const short8*)(Bs + (wn * 64 + nt * 16 + col) * 64 + csw);
#pragma unroll
            for (int mt = 0; mt < 4; mt++)
#pragma unroll
                for (int nt = 0; nt < 4; nt++)
                    acc[mt][nt] = __builtin_amdgcn_mfma_f32_16x16x32_bf16(af[mt], bfr[nt], acc[mt][nt], 0, 0, 0);
        }
    }

    unsigned short* Hout = (blockIdx.z == 0) ? Qh : (blockIdx.z == 1) ? Kh : Vf;
#pragma unroll
    for (int mt = 0; mt < 4; mt++)
#pragma unroll
        for (int nt = 0; nt < 4; nt++)
#pragma unroll
            for (int reg = 0; reg < 4; reg++) {
                long long row = row0 + wm * 64 + mt * 16 + quad * 4 + reg;
                int c = col0 + wn * 64 + nt * 16 + col;
                float v = acc[mt][nt][reg];
                if (blockIdx.z == 3) EP[row * N + c] = v + ep_b[c];
                else                 Hout[row * N + c] = f2bf(v);
            }
}

// ---------------- LayerNorm rows ----------------
__global__ __launch_bounds__(256) void ln_rows(
    const float* __restrict__ in, const float* __restrict__ res,
    const float* __restrict__ g, const float* __restrict__ bta,
    float* __restrict__ outf, unsigned short* __restrict__ outh)
{
    const long long row = blockIdx.x;
    const float* ip = in + row * D_MODEL;
    const float* rp = res ? res + row * D_MODEL : nullptr;
    const int tid = threadIdx.x;
    float vals[4];
    float s = 0.f, ss = 0.f;
#pragma unroll
    for (int j = 0; j < 4; j++) {
        int idx = tid + j * 256;
        float v = ip[idx];
        if (rp) v += rp[idx];
        vals[j] = v; s += v; ss += v * v;
    }
    __shared__ float sred[4], ssred[4];
    s = waveReduceSum(s); ss = waveReduceSum(ss);
    int wave = tid >> 6, lane = tid & 63;
    if (lane == 0) { sred[wave] = s; ssred[wave] = ss; }
    __syncthreads();
    float ts = sred[0] + sred[1] + sred[2] + sred[3];
    float tss = ssred[0] + ssred[1] + ssred[2] + ssred[3];
    float mu = ts * (1.f / D_MODEL);
    float var = tss * (1.f / D_MODEL) - mu * mu;
    float rs = rsqrtf(var + LN_EPS);
#pragma unroll
    for (int j = 0; j < 4; j++) {
        int idx = tid + j * 256;
        float o = (vals[j] - mu) * rs * g[idx] + bta[idx];
        if (outf) outf[row * D_MODEL + idx] = o;
        else      outh[row * D_MODEL + idx] = f2bf(o);
    }
}

// ---------------- V transpose ----------------
__global__ __launch_bounds__(256) void transpose_v(
    const unsigned short* __restrict__ V, unsigned short* __restrict__ Vt)
{
    const int m0 = blockIdx.x * 64, h = blockIdx.y, b = blockIdx.z;
    __shared__ unsigned int t[64][65];
    const int tid = threadIdx.x;
    {
        int r = tid >> 4, c4 = (tid & 15) * 4;
#pragma unroll
        for (int i = 0; i < 4; i++) {
            int row = r + i * 16;
            ushort4 v = *(const ushort4*)(V + ((long long)b * L_SEQ + m0 + row) * D_MODEL + h * DK + c4);
            t[row][c4] = v.x; t[row][c4 + 1] = v.y; t[row][c4 + 2] = v.z; t[row][c4 + 3] = v.w;
        }
    }
    __syncthreads();
    const int lane = tid & 63, wv = tid >> 6;
#pragma unroll
    for (int i = 0; i < 16; i++) {
        int d = wv * 16 + i;
        Vt[(((long long)(b * NUM_HEADS + h)) * DK + d) * L_SEQ + m0 + lane] = (unsigned short)t[lane][d];
    }
}

// ---------------- stats: EB row max (bf16 input) ----------------
__global__ __launch_bounds__(256) void eb_stats(
    const unsigned short* __restrict__ EBh, float* __restrict__ ebmax)
{
    const long long row = blockIdx.x;
    const unsigned short* p = EBh + row * L_SEQ;
    const int tid = threadIdx.x;
    short8 v = *(const short8*)(p + tid * 8);
    float m = bf2f((unsigned short)v[0]);
#pragma unroll
    for (int j = 1; j < 8; j++) m = fmaxf(m, bf2f((unsigned short)v[j]));
#pragma unroll
    for (int off = 32; off > 0; off >>= 1) m = fmaxf(m, __shfl_xor(m, off, 64));
    __shared__ float red[4];
    if ((tid & 63) == 0) red[tid >> 6] = m;
    __syncthreads();
    if (tid == 0)
        ebmax[row] = fmaxf(fmaxf(red[0], red[1]), fmaxf(red[2], red[3]));
}

// ---------------- stats: qn/kn per (b,h,l) ----------------
__global__ __launch_bounds__(256) void qk_stats(
    const unsigned short* __restrict__ Qh, const unsigned short* __restrict__ Kh,
    float* __restrict__ qn, float* __restrict__ kn)
{
    const int l0 = blockIdx.x * 64, h = blockIdx.y, b = blockIdx.z;
    const int tid = threadIdx.x;
    const int r = tid >> 2, p4 = (tid & 3) * 16;
    const unsigned short* q = Qh + ((long long)b * L_SEQ + l0 + r) * D_MODEL + h * DK + p4;
    const unsigned short* k = Kh + ((long long)b * L_SEQ + l0 + r) * D_MODEL + h * DK + p4;
    float sq = 0.f, sk = 0.f;
#pragma unroll
    for (int i = 0; i < 16; i++) {
        float qv = bf2f(q[i]); sq += qv * qv;
        float kv = bf2f(k[i]); sk += kv * kv;
    }
    sq += __shfl_xor(sq, 1, 64); sq += __shfl_xor(sq, 2, 64);
    sk += __shfl_xor(sk, 1, 64); sk += __shfl_xor(sk, 2, 64);
    if ((tid & 3) == 0) {
        long long idx = ((long long)(b * NUM_HEADS + h)) * L_SEQ + l0 + r;
        qn[idx] = sqrtf(sq);
        kn[idx] = sqrtf(sk);
    }
}

// ---------------- stats: per-(b,h) k-norm global max ----------------
__global__ __launch_bounds__(256) void kstats2(
    const float* __restrict__ kn, float* __restrict__ kmax)
{
    const long long bh = blockIdx.x;
    const float* p = kn + bh * L_SEQ;
    const int tid = threadIdx.x;
    float4 a = *(const float4*)(p + tid * 8);
    float4 c = *(const float4*)(p + tid * 8 + 4);
    float m = fmaxf(fmaxf(fmaxf(a.x, a.y), fmaxf(a.z, a.w)),
                    fmaxf(fmaxf(c.x, c.y), fmaxf(c.z, c.w)));
#pragma unroll
    for (int off = 32; off > 0; off >>= 1) m = fmaxf(m, __shfl_xor(m, off, 64));
    __shared__ float red[4];
    if ((tid & 63) == 0) red[tid >> 6] = m;
    __syncthreads();
    if (tid == 0)
        kmax[bh] = fmaxf(fmaxf(red[0], red[1]), fmaxf(red[2], red[3]));
}

// ---------------- MFMA attention: async double-buffered K staging, single-barrier
//                  pass 1, overlapped V staging + deferred p stores in pass 2.
//                  EB consumed as bf16; skip machinery removed (never fires on
//                  this distribution; computing all tiles is exact). ----------------
__global__ __launch_bounds__(256) void attn_mfma(
    const unsigned short* __restrict__ Qh, const unsigned short* __restrict__ Kh,
    const unsigned short* __restrict__ Vt, const unsigned short* __restrict__ EBh,
    const float* __restrict__ ebmax, const float* __restrict__ qn,
    const float* __restrict__ kmax,
    float* __restrict__ attn_out, unsigned short* __restrict__ CTXh)
{
    // Linear LDS tiles (global_load_lds destinations must be linear) with
    // source-side XOR swizzle: LDS[row][chunk] = G[row][chunk ^ (row&7)],
    // chunks of 8 bf16 (16 B). Same pattern as the verified GEMM kernels.
    __shared__ unsigned short Ks[2][64 * 64];   // K tile double buffer (16 KB)
    __shared__ unsigned short Vts[64 * 64];     // V tile single buffer  (8 KB)
    __shared__ unsigned short Ps[4 * 16 * 72];  // per-wave P scratch    (9 KB)

    const int tid = threadIdx.x;
    const int lane = tid & 63, w = tid >> 6;
    const int quad = lane >> 4, col = lane & 15;
    const int l0 = blockIdx.x * 64;
    const int h = blockIdx.y, b = blockIdx.z;

    const unsigned short* kbase = Kh + ((long long)b * L_SEQ) * D_MODEL + h * DK;
    const unsigned short* vbase = Vt + ((long long)(b * NUM_HEADS + h)) * DK * L_SEQ;

    const int lr = lane >> 3, lc = lane & 7;
    const int gsw = (lc ^ lr) * 8;       // swizzled global chunk offset (shorts)

    // ---- prologue: issue first K stage ASAP (async DMA) ----
#pragma unroll
    for (int p = 0; p < 2; p++) {
        const int rb = w * 8 + p * 32;
        __builtin_amdgcn_global_load_lds(
            (gas_u32*)(kbase + (long long)(rb + lr) * D_MODEL + gsw),
            (las_u32*)(&Ks[0][rb * 64]), 16, 0, 0);
    }

    short8 aq[2];
    {
        const unsigned short* qrow = Qh + ((long long)b * L_SEQ + l0 + w * 16 + col) * D_MODEL + h * DK;
        aq[0] = *(const short8*)(qrow + quad * 8);
        aq[1] = *(const short8*)(qrow + 32 + quad * 8);
    }

    float Mhat[4];
    {
        const float km = kmax[b * NUM_HEADS + h];
#pragma unroll
        for (int reg = 0; reg < 4; reg++) {
            int row = l0 + w * 16 + quad * 4 + reg;
            float qb = qn[((long long)(b * NUM_HEADS + h)) * L_SEQ + row];
            Mhat[reg] = ENERGY_SCALE * ebmax[(long long)b * L_SEQ + row] +
                        qb * km * 0.125f + 0.02f;
        }
    }

    const unsigned short* ebp = EBh + ((long long)b * L_SEQ + l0 + w * 16 + quad * 4) * L_SEQ + col;

    __syncthreads();   // drains prologue stage (vmcnt) + joins waves

    // ---- pass 1: rowS over all tiles, ONE barrier per tile, K prefetched ----
    float rowSacc[4] = {0.f, 0.f, 0.f, 0.f};
    int cur = 0;
    for (int t = 0; t < 32; t++) {
        if (t < 31) {
#pragma unroll
            for (int p = 0; p < 2; p++) {
                const int rb = w * 8 + p * 32;
                __builtin_amdgcn_global_load_lds(
                    (gas_u32*)(kbase + (long long)((t + 1) * 64 + rb + lr) * D_MODEL + gsw),
                    (las_u32*)(&Ks[cur ^ 1][rb * 64]), 16, 0, 0);
            }
        }
        const int m0 = t * 64;

        f32x4 acc[4];
#pragma unroll
        for (int nt = 0; nt < 4; nt++) acc[nt] = (f32x4){0.f, 0.f, 0.f, 0.f};
        __builtin_amdgcn_s_setprio(1);
#pragma unroll
        for (int nt = 0; nt < 4; nt++)
#pragma unroll
            for (int kc = 0; kc < 2; kc++) {
                short8 bk = *(const short8*)(&Ks[cur][((nt * 16 + col) << 6) +
                                                     (((quad + 4 * kc) ^ (col & 7)) << 3)]);
                acc[nt] = __builtin_amdgcn_mfma_f32_16x16x32_bf16(aq[kc], bk, acc[nt], 0, 0, 0);
            }
        __builtin_amdgcn_s_setprio(0);
#pragma unroll
        for (int nt = 0; nt < 4; nt++)
#pragma unroll
            for (int reg = 0; reg < 4; reg++) {
                float e = bf2f(ebp[(long long)reg * L_SEQ + m0 + nt * 16]);
                float s = acc[nt][reg] * 0.125f + ENERGY_SCALE * e;
                rowSacc[reg] += __expf(s - Mhat[reg]);
            }
        __syncthreads();   // next K landed; Ks[cur] free for overwrite next iter
        cur ^= 1;
    }

    float invS[4];
#pragma unroll
    for (int reg = 0; reg < 4; reg++) {
        float v = rowSacc[reg];
#pragma unroll
        for (int off = 8; off > 0; off >>= 1) v += __shfl_xor(v, off, 64);
        invS[reg] = 1.f / v;
    }

    // ---- pass 2 prologue: restage first K tile ----
    cur = 0;
#pragma unroll
    for (int p = 0; p < 2; p++) {
        const int rb = w * 8 + p * 32;
        __builtin_amdgcn_global_load_lds(
            (gas_u32*)(kbase + (long long)(rb + lr) * D_MODEL + gsw),
            (las_u32*)(&Ks[0][rb * 64]), 16, 0, 0);
    }
    __syncthreads();

    // ---- pass 2: p writes + ctx = P V; V staged async under QK, p stores after barrier ----
    f32x4 ctx[4];
#pragma unroll
    for (int nt = 0; nt < 4; nt++) ctx[nt] = (f32x4){0.f, 0.f, 0.f, 0.f};

    unsigned short* Psw = Ps + w * 16 * 72;
    float* aob = attn_out + (((long long)(b * NUM_HEADS + h)) * L_SEQ + l0 + w * 16 + quad * 4) * L_SEQ + col;

    for (int t = 0; t < 32; t++) {
        const int m0 = t * 64;

        // stage V(t) — hidden under the QK phase below
#pragma unroll
        for (int p = 0; p < 2; p++) {
            const int rb = w * 8 + p * 32;
            __builtin_amdgcn_global_load_lds(
                (gas_u32*)(vbase + (long long)(rb + lr) * L_SEQ + m0 + gsw),
                (las_u32*)(&Vts[rb * 64]), 16, 0, 0);
        }
        // prefetch next K tile
        if (t < 31) {
#pragma unroll
            for (int p = 0; p < 2; p++) {
                const int rb = w * 8 + p * 32;
                __builtin_amdgcn_global_load_lds(
                    (gas_u32*)(kbase + (long long)((t + 1) * 64 + rb + lr) * D_MODEL + gsw),
                    (las_u32*)(&Ks[cur ^ 1][rb * 64]), 16, 0, 0);
            }
        }

        f32x4 acc[4];
#pragma unroll
        for (int nt = 0; nt < 4; nt++) acc[nt] = (f32x4){0.f, 0.f, 0.f, 0.f};
        __builtin_amdgcn_s_setprio(1);
#pragma unroll
        for (int nt = 0; nt < 4; nt++)
#pragma unroll
            for (int kc = 0; kc < 2; kc++) {
                short8 bk = *(const short8*)(&Ks[cur][((nt * 16 + col) << 6) +
                                                     (((quad + 4 * kc) ^ (col & 7)) << 3)]);
                acc[nt] = __builtin_amdgcn_mfma_f32_16x16x32_bf16(aq[kc], bk, acc[nt], 0, 0, 0);
            }
        __builtin_amdgcn_s_setprio(0);

        // transform scores -> normalized p in-place; write P to per-wave LDS scratch
#pragma unroll
        for (int nt = 0; nt < 4; nt++)
#pragma unroll
            for (int reg = 0; reg < 4; reg++) {
                float e = bf2f(ebp[(long long)reg * L_SEQ + m0 + nt * 16]);
                float s = acc[nt][reg] * 0.125f + ENERGY_SCALE * e;
                float p = __expf(s - Mhat[reg]) * invS[reg];
                acc[nt][reg] = p;
                Psw[(quad * 4 + reg) * 72 + nt * 16 + col] = f2bf(p);
            }
        __syncthreads();   // V tile landed (and next K issued early)

        // global p stores issued now — they drain during the PV phase
#pragma unroll
        for (int nt = 0; nt < 4; nt++)
#pragma unroll
            for (int reg = 0; reg < 4; reg++)
                aob[(long long)reg * L_SEQ + m0 + nt * 16] = acc[nt][reg];

        short8 ap[2];
#pragma unroll
        for (int kc = 0; kc < 2; kc++)
            ap[kc] = *(const short8*)(Psw + col * 72 + quad * 8 + kc * 32);
        __builtin_amdgcn_s_setprio(1);
#pragma unroll
        for (int nt = 0; nt < 4; nt++)
#pragma unroll
            for (int kc = 0; kc < 2; kc++) {
                short8 bv = *(const short8*)(&Vts[((nt * 16 + col) << 6) +
                                                  (((quad + 4 * kc) ^ (col & 7)) << 3)]);
                ctx[nt] = __builtin_amdgcn_mfma_f32_16x16x32_bf16(ap[kc], bv, ctx[nt], 0, 0, 0);
            }
        __builtin_amdgcn_s_setprio(0);
        __syncthreads();   // protect Vts (and Ps) against next-iter overwrite
        cur ^= 1;
    }

#pragma unroll
    for (int nt = 0; nt < 4; nt++)
#pragma unroll
        for (int reg = 0; reg < 4; reg++)
            CTXh[((long long)b * L_SEQ + l0 + w * 16 + quad * 4 + reg) * D_MODEL + h * DK + nt * 16 + col] =
                f2bf(ctx[nt][reg]);
}

extern "C" void kernel_launch(void* const* d_in, const int* in_sizes, int n_in,
                              void* d_out, int out_size, void* d_ws, size_t ws_size,
                              hipStream_t stream) {
    const float* x    = (const float*)d_in[0];
    const float* wq   = (const float*)d_in[1];
    const float* wk   = (const float*)d_in[2];
    const float* wv   = (const float*)d_in[3];
    const float* wo_w = (const float*)d_in[4];
    const float* wo_b = (const float*)d_in[5];
    const float* ep_w = (const float*)d_in[6];
    const float* ep_b = (const float*)d_in[7];
    const float* en_g = (const float*)d_in[8];
    const float* en_b = (const float*)d_in[9];
    const float* ln_g = (const float*)d_in[10];
    const float* ln_b = (const float*)d_in[11];

    float* out_final = (float*)d_out;
    float* attn_out  = out_final + (long long)BATCH * L_SEQ * D_MODEL;

    const long long MD = (long long)BATCH * L_SEQ * D_MODEL;   // 4,194,304
    const long long WN = (long long)D_MODEL * D_MODEL;         // 1,048,576
    const long long BH = (long long)BATCH * NUM_HEADS;
    const long long LL = (long long)BATCH * L_SEQ * L_SEQ;     // 8,388,608

    unsigned short* EBh = (unsigned short*)d_ws;               // [B,L,L] bf16
    float* EP = (float*)(EBh + LL);                            // MD fp32 (also OUT)
    unsigned short* Xh   = (unsigned short*)(EP + MD);
    unsigned short* Qh   = Xh + MD;
    unsigned short* Kh   = Qh + MD;
    unsigned short* Vf   = Kh + MD;
    unsigned short* Vt   = Vf + MD;
    unsigned short* EFh  = Vt + MD;
    unsigned short* CTXh = EFh + MD;
    unsigned short* wqh  = CTXh + MD;
    unsigned short* wkh  = wqh + WN;
    unsigned short* wvh  = wkh + WN;
    unsigned short* eph  = wvh + WN;
    unsigned short* woh  = eph + WN;
    float* ebmax  = (float*)(woh + WN);                        // B*L
    float* qn     = ebmax + (long long)BATCH * L_SEQ;          // B*H*L
    float* kn     = qn + BH * L_SEQ;                           // B*H*L
    float* kmax   = kn + BH * L_SEQ;                           // B*H
    float* OUT = EP;                                           // EP dead after ln

    const int M = BATCH * L_SEQ;                               // 4096
    dim3 blk(256);

    cvt6<<<dim3((unsigned)(MD / 1024), 6), blk, 0, stream>>>(
        x, wq, wk, wv, ep_w, wo_w, Xh, wqh, wkh, wvh, eph, woh,
        MD, WN, WN, WN, WN, WN);

    proj_gemm<<<dim3(D_MODEL / 128, M / 128, 4), blk, 0, stream>>>(
        Xh, wqh, wkh, wvh, eph, ep_b, Qh, Kh, Vf, EP);

    ln_rows<<<dim3(M), blk, 0, stream>>>(EP, nullptr, en_g, en_b, nullptr, EFh);

    gemm_bf16<<<dim3(L_SEQ / 128, L_SEQ / 128, BATCH), blk, 0, stream>>>(
        EFh, EFh, nullptr, nullptr, EBh, L_SEQ, D_MODEL,
        (long long)L_SEQ * D_MODEL, (long long)L_SEQ * D_MODEL,
        (long long)L_SEQ * L_SEQ);

    qk_stats<<<dim3(L_SEQ / 64, NUM_HEADS, BATCH), blk, 0, stream>>>(Qh, Kh, qn, kn);
    kstats2<<<dim3((unsigned)BH), blk, 0, stream>>>(kn, kmax);
    eb_stats<<<dim3(M), blk, 0, stream>>>(EBh, ebmax);

    transpose_v<<<dim3(L_SEQ / 64, NUM_HEADS, BATCH), blk, 0, stream>>>(Vf, Vt);

    attn_mfma<<<dim3(L_SEQ / 64, NUM_HEADS, BATCH), blk, 0, stream>>>(
        Qh, Kh, Vt, EBh, ebmax, qn, kmax, attn_out, CTXh);

    gemm_bf16<<<dim3(D_MODEL / 128, M / 128, 1), blk, 0, stream>>>(
        CTXh, woh, wo_b, OUT, nullptr, D_MODEL, D_MODEL, 0, 0, 0);

    ln_rows<<<dim3(M), blk, 0, stream>>>(OUT, x, ln_g, ln_b, out_final, nullptr);
}

// Round 3
// 749.241 us; speedup vs baseline: 1.2417x; 1.2417x over previous
//
#include <hip/hip_runtime.h>
#include <math.h>

#define D_MODEL 1024
#define NUM_HEADS 16
#define DK 64
#define L_SEQ 2048
#define BATCH 2
#define LN_EPS 1e-5f
#define ENERGY_SCALE 0.1f

typedef __attribute__((ext_vector_type(8))) short short8;
typedef __attribute__((ext_vector_type(4))) float f32x4;
typedef __attribute__((address_space(1))) const unsigned int gas_u32;
typedef __attribute__((address_space(3))) unsigned int las_u32;

__device__ __forceinline__ float waveReduceSum(float v) {
#pragma unroll
    for (int off = 32; off > 0; off >>= 1) v += __shfl_xor(v, off, 64);
    return v;
}

__device__ __forceinline__ unsigned short f2bf(float f) {
    unsigned int u = __float_as_uint(f);
    u += 0x7fff + ((u >> 16) & 1);          // round-to-nearest-even
    return (unsigned short)(u >> 16);
}
__device__ __forceinline__ float bf2f(unsigned short u) {
    return __uint_as_float((unsigned int)u << 16);
}

// ---------------- fp32 -> bf16 convert, 6 matrices in one launch ----------------
__global__ __launch_bounds__(256) void cvt6(
    const float* s0, const float* s1, const float* s2,
    const float* s3, const float* s4, const float* s5,
    unsigned short* d0, unsigned short* d1, unsigned short* d2,
    unsigned short* d3, unsigned short* d4, unsigned short* d5,
    long long n0, long long n1, long long n2, long long n3, long long n4, long long n5)
{
    const float* s; unsigned short* d; long long n;
    switch (blockIdx.y) {
        case 0: s = s0; d = d0; n = n0; break;
        case 1: s = s1; d = d1; n = n1; break;
        case 2: s = s2; d = d2; n = n2; break;
        case 3: s = s3; d = d3; n = n3; break;
        case 4: s = s4; d = d4; n = n4; break;
        default: s = s5; d = d5; n = n5; break;
    }
    long long i = ((long long)blockIdx.x * 256 + threadIdx.x) * 4;
    if (i >= n) return;
    float4 v = *(const float4*)(s + i);
    ushort4 o;
    o.x = f2bf(v.x); o.y = f2bf(v.y); o.z = f2bf(v.z); o.w = f2bf(v.w);
    *(ushort4*)(d + i) = o;
}

// ---------------- bf16 MFMA GEMM with global_load_lds (round-8 verified) ----------------
__global__ __launch_bounds__(256) void gemm_bf16(
    const unsigned short* __restrict__ A, const unsigned short* __restrict__ B,
    const float* __restrict__ bias, float* __restrict__ Cf, unsigned short* __restrict__ Ch,
    int N, int K, long long sA, long long sB, long long sC)
{
    A += (long long)blockIdx.z * sA;
    B += (long long)blockIdx.z * sB;
    __shared__ unsigned short As[128 * 64];
    __shared__ unsigned short Bs[128 * 64];
    const int tid = threadIdx.x;
    const int lane = tid & 63, w = tid >> 6;
    const int quad = lane >> 4, col = lane & 15;
    const int wm = w & 1, wn = w >> 1;
    const int row0 = blockIdx.y * 128, col0 = blockIdx.x * 128;

    const int lr = lane >> 3, lc = lane & 7;
    const int gcs = (lc ^ lr) * 8;

    f32x4 acc[4][4];
#pragma unroll
    for (int mt = 0; mt < 4; mt++)
#pragma unroll
        for (int nt = 0; nt < 4; nt++) acc[mt][nt] = (f32x4){0.f, 0.f, 0.f, 0.f};

    for (int k0 = 0; k0 < K; k0 += 64) {
        __syncthreads();
#pragma unroll
        for (int p = 0; p < 4; p++) {
            const int rb = w * 32 + p * 8;
            __builtin_amdgcn_global_load_lds(
                (gas_u32*)(A + (long long)(row0 + rb + lr) * K + k0 + gcs),
                (las_u32*)(As + rb * 64), 16, 0, 0);
            __builtin_amdgcn_global_load_lds(
                (gas_u32*)(B + (long long)(col0 + rb + lr) * K + k0 + gcs),
                (las_u32*)(Bs + rb * 64), 16, 0, 0);
        }
        __syncthreads();
#pragma unroll
        for (int kc = 0; kc < 2; kc++) {
            const int csw = ((quad + 4 * kc) ^ (col & 7)) * 8;
            short8 af[4], bfr[4];
#pragma unroll
            for (int mt = 0; mt < 4; mt++)
                af[mt] = *(const short8*)(As + (wm * 64 + mt * 16 + col) * 64 + csw);
#pragma unroll
            for (int nt = 0; nt < 4; nt++)
                bfr[nt] = *(const short8*)(Bs + (wn * 64 + nt * 16 + col) * 64 + csw);
#pragma unroll
            for (int mt = 0; mt < 4; mt++)
#pragma unroll
                for (int nt = 0; nt < 4; nt++)
                    acc[mt][nt] = __builtin_amdgcn_mfma_f32_16x16x32_bf16(af[mt], bfr[nt], acc[mt][nt], 0, 0, 0);
        }
    }

#pragma unroll
    for (int mt = 0; mt < 4; mt++)
#pragma unroll
        for (int nt = 0; nt < 4; nt++)
#pragma unroll
            for (int reg = 0; reg < 4; reg++) {
                long long row = row0 + wm * 64 + mt * 16 + quad * 4 + reg;
                int c = col0 + wn * 64 + nt * 16 + col;
                float v = acc[mt][nt][reg];
                if (bias) v += bias[c];
                if (Cf) Cf[blockIdx.z * sC + row * N + c] = v;
                else    Ch[blockIdx.z * sC + row * N + c] = f2bf(v);
            }
}

// ---------------- fused projections with global_load_lds (round-8 verified) ----------------
__global__ __launch_bounds__(256) void proj_gemm(
    const unsigned short* __restrict__ Xh,
    const unsigned short* __restrict__ wqh, const unsigned short* __restrict__ wkh,
    const unsigned short* __restrict__ wvh, const unsigned short* __restrict__ eph,
    const float* __restrict__ ep_b,
    unsigned short* __restrict__ Qh, unsigned short* __restrict__ Kh,
    unsigned short* __restrict__ Vf, float* __restrict__ EP)
{
    const unsigned short* B;
    switch (blockIdx.z) {
        case 0: B = wqh; break;
        case 1: B = wkh; break;
        case 2: B = wvh; break;
        default: B = eph; break;
    }
    __shared__ unsigned short As[128 * 64];
    __shared__ unsigned short Bs[128 * 64];
    const int tid = threadIdx.x;
    const int lane = tid & 63, w = tid >> 6;
    const int quad = lane >> 4, col = lane & 15;
    const int wm = w & 1, wn = w >> 1;
    const int row0 = blockIdx.y * 128, col0 = blockIdx.x * 128;
    const int K = D_MODEL, N = D_MODEL;

    const int lr = lane >> 3, lc = lane & 7;
    const int gcs = (lc ^ lr) * 8;

    f32x4 acc[4][4];
#pragma unroll
    for (int mt = 0; mt < 4; mt++)
#pragma unroll
        for (int nt = 0; nt < 4; nt++) acc[mt][nt] = (f32x4){0.f, 0.f, 0.f, 0.f};

    for (int k0 = 0; k0 < K; k0 += 64) {
        __syncthreads();
#pragma unroll
        for (int p = 0; p < 4; p++) {
            const int rb = w * 32 + p * 8;
            __builtin_amdgcn_global_load_lds(
                (gas_u32*)(Xh + (long long)(row0 + rb + lr) * K + k0 + gcs),
                (las_u32*)(As + rb * 64), 16, 0, 0);
            __builtin_amdgcn_global_load_lds(
                (gas_u32*)(B + (long long)(col0 + rb + lr) * K + k0 + gcs),
                (las_u32*)(Bs + rb * 64), 16, 0, 0);
        }
        __syncthreads();
#pragma unroll
        for (int kc = 0; kc < 2; kc++) {
            const int csw = ((quad + 4 * kc) ^ (col & 7)) * 8;
            short8 af[4], bfr[4];
#pragma unroll
            for (int mt = 0; mt < 4; mt++)
                af[mt] = *(const short8*)(As + (wm * 64 + mt * 16 + col) * 64 + csw);
#pragma unroll
            for (int nt = 0; nt < 4; nt++)
                bfr[nt] = *(const short8*)(Bs + (wn * 64 + nt * 16 + col) * 64 + csw);
#pragma unroll
            for (int mt = 0; mt < 4; mt++)
#pragma unroll
                for (int nt = 0; nt < 4; nt++)
                    acc[mt][nt] = __builtin_amdgcn_mfma_f32_16x16x32_bf16(af[mt], bfr[nt], acc[mt][nt], 0, 0, 0);
        }
    }

    unsigned short* Hout = (blockIdx.z == 0) ? Qh : (blockIdx.z == 1) ? Kh : Vf;
#pragma unroll
    for (int mt = 0; mt < 4; mt++)
#pragma unroll
        for (int nt = 0; nt < 4; nt++)
#pragma unroll
            for (int reg = 0; reg < 4; reg++) {
                long long row = row0 + wm * 64 + mt * 16 + quad * 4 + reg;
                int c = col0 + wn * 64 + nt * 16 + col;
                float v = acc[mt][nt][reg];
                if (blockIdx.z == 3) EP[row * N + c] = v + ep_b[c];
                else                 Hout[row * N + c] = f2bf(v);
            }
}

// ---------------- LayerNorm rows ----------------
__global__ __launch_bounds__(256) void ln_rows(
    const float* __restrict__ in, const float* __restrict__ res,
    const float* __restrict__ g, const float* __restrict__ bta,
    float* __restrict__ outf, unsigned short* __restrict__ outh)
{
    const long long row = blockIdx.x;
    const float* ip = in + row * D_MODEL;
    const float* rp = res ? res + row * D_MODEL : nullptr;
    const int tid = threadIdx.x;
    float vals[4];
    float s = 0.f, ss = 0.f;
#pragma unroll
    for (int j = 0; j < 4; j++) {
        int idx = tid + j * 256;
        float v = ip[idx];
        if (rp) v += rp[idx];
        vals[j] = v; s += v; ss += v * v;
    }
    __shared__ float sred[4], ssred[4];
    s = waveReduceSum(s); ss = waveReduceSum(ss);
    int wave = tid >> 6, lane = tid & 63;
    if (lane == 0) { sred[wave] = s; ssred[wave] = ss; }
    __syncthreads();
    float ts = sred[0] + sred[1] + sred[2] + sred[3];
    float tss = ssred[0] + ssred[1] + ssred[2] + ssred[3];
    float mu = ts * (1.f / D_MODEL);
    float var = tss * (1.f / D_MODEL) - mu * mu;
    float rs = rsqrtf(var + LN_EPS);
#pragma unroll
    for (int j = 0; j < 4; j++) {
        int idx = tid + j * 256;
        float o = (vals[j] - mu) * rs * g[idx] + bta[idx];
        if (outf) outf[row * D_MODEL + idx] = o;
        else      outh[row * D_MODEL + idx] = f2bf(o);
    }
}

// ---------------- V transpose ----------------
__global__ __launch_bounds__(256) void transpose_v(
    const unsigned short* __restrict__ V, unsigned short* __restrict__ Vt)
{
    const int m0 = blockIdx.x * 64, h = blockIdx.y, b = blockIdx.z;
    __shared__ unsigned int t[64][65];
    const int tid = threadIdx.x;
    {
        int r = tid >> 4, c4 = (tid & 15) * 4;
#pragma unroll
        for (int i = 0; i < 4; i++) {
            int row = r + i * 16;
            ushort4 v = *(const ushort4*)(V + ((long long)b * L_SEQ + m0 + row) * D_MODEL + h * DK + c4);
            t[row][c4] = v.x; t[row][c4 + 1] = v.y; t[row][c4 + 2] = v.z; t[row][c4 + 3] = v.w;
        }
    }
    __syncthreads();
    const int lane = tid & 63, wv = tid >> 6;
#pragma unroll
    for (int i = 0; i < 16; i++) {
        int d = wv * 16 + i;
        Vt[(((long long)(b * NUM_HEADS + h)) * DK + d) * L_SEQ + m0 + lane] = (unsigned short)t[lane][d];
    }
}

// ---------------- stats: EB row max + per-64-tile max (bf16 input), one pass ----------------
__global__ __launch_bounds__(256) void eb_stats(
    const unsigned short* __restrict__ EBh, float* __restrict__ ebmax, float* __restrict__ ebtmax)
{
    const long long row = blockIdx.x;
    const unsigned short* p = EBh + row * L_SEQ;
    const int tid = threadIdx.x;
    short8 v = *(const short8*)(p + tid * 8);
    float m = bf2f((unsigned short)v[0]);
#pragma unroll
    for (int j = 1; j < 8; j++) m = fmaxf(m, bf2f((unsigned short)v[j]));
    m = fmaxf(m, __shfl_xor(m, 1, 64));
    m = fmaxf(m, __shfl_xor(m, 2, 64));
    m = fmaxf(m, __shfl_xor(m, 4, 64));
    if ((tid & 7) == 0) ebtmax[row * 32 + (tid >> 3)] = m;
    m = fmaxf(m, __shfl_xor(m, 8, 64));
    m = fmaxf(m, __shfl_xor(m, 16, 64));
    m = fmaxf(m, __shfl_xor(m, 32, 64));
    __shared__ float red[4];
    if ((tid & 63) == 0) red[tid >> 6] = m;
    __syncthreads();
    if (tid == 0)
        ebmax[row] = fmaxf(fmaxf(red[0], red[1]), fmaxf(red[2], red[3]));
}

// ---------------- stats: qn/kn per (b,h,l) ----------------
__global__ __launch_bounds__(256) void qk_stats(
    const unsigned short* __restrict__ Qh, const unsigned short* __restrict__ Kh,
    float* __restrict__ qn, float* __restrict__ kn)
{
    const int l0 = blockIdx.x * 64, h = blockIdx.y, b = blockIdx.z;
    const int tid = threadIdx.x;
    const int r = tid >> 2, p4 = (tid & 3) * 16;
    const unsigned short* q = Qh + ((long long)b * L_SEQ + l0 + r) * D_MODEL + h * DK + p4;
    const unsigned short* k = Kh + ((long long)b * L_SEQ + l0 + r) * D_MODEL + h * DK + p4;
    float sq = 0.f, sk = 0.f;
#pragma unroll
    for (int i = 0; i < 16; i++) {
        float qv = bf2f(q[i]); sq += qv * qv;
        float kv = bf2f(k[i]); sk += kv * kv;
    }
    sq += __shfl_xor(sq, 1, 64); sq += __shfl_xor(sq, 2, 64);
    sk += __shfl_xor(sk, 1, 64); sk += __shfl_xor(sk, 2, 64);
    if ((tid & 3) == 0) {
        long long idx = ((long long)(b * NUM_HEADS + h)) * L_SEQ + l0 + r;
        qn[idx] = sqrtf(sq);
        kn[idx] = sqrtf(sk);
    }
}

// ---------------- stats: per-(b,h) k-norm global + per-tile max ----------------
__global__ __launch_bounds__(256) void kstats2(
    const float* __restrict__ kn, float* __restrict__ kmax, float* __restrict__ ktmax)
{
    const long long bh = blockIdx.x;
    const float* p = kn + bh * L_SEQ;
    const int tid = threadIdx.x;
    float4 a = *(const float4*)(p + tid * 8);
    float4 c = *(const float4*)(p + tid * 8 + 4);
    float m = fmaxf(fmaxf(fmaxf(a.x, a.y), fmaxf(a.z, a.w)),
                    fmaxf(fmaxf(c.x, c.y), fmaxf(c.z, c.w)));
    m = fmaxf(m, __shfl_xor(m, 1, 64));
    m = fmaxf(m, __shfl_xor(m, 2, 64));
    m = fmaxf(m, __shfl_xor(m, 4, 64));
    if ((tid & 7) == 0) ktmax[bh * 32 + (tid >> 3)] = m;
    m = fmaxf(m, __shfl_xor(m, 8, 64));
    m = fmaxf(m, __shfl_xor(m, 16, 64));
    m = fmaxf(m, __shfl_xor(m, 32, 64));
    __shared__ float red[4];
    if ((tid & 63) == 0) red[tid >> 6] = m;
    __syncthreads();
    if (tid == 0)
        kmax[bh] = fmaxf(fmaxf(red[0], red[1]), fmaxf(red[2], red[3]));
}

// ---------------- skip mask ----------------
__global__ __launch_bounds__(64) void skip_mask(
    const float* __restrict__ ebmax, const float* __restrict__ ebtmax,
    const float* __restrict__ qn, const float* __restrict__ kmax,
    const float* __restrict__ ktmax, unsigned int* __restrict__ skipm)
{
    const int l0 = blockIdx.x * 64, h = blockIdx.y, b = blockIdx.z;
    const int tid = threadIdx.x;
    const int row = l0 + tid;
    const int bh = b * NUM_HEADS + h;
    float q = qn[(long long)bh * L_SEQ + row];
    float Mh = ENERGY_SCALE * ebmax[(long long)b * L_SEQ + row] + q * kmax[bh] * 0.125f + 0.02f;
    const float* ebt = ebtmax + ((long long)b * L_SEQ + row) * 32;
    const float* ktm = ktmax + bh * 32;
    unsigned int m = 0;
    for (int t = 0; t < 32; t++) {
        float ub = ENERGY_SCALE * ebt[t] + q * ktm[t] * 0.125f;
        unsigned long long bal = __ballot(ub < Mh - 45.0f);
        if (bal == ~0ull) m |= (1u << t);
    }
    if (tid == 0) skipm[bh * 32 + blockIdx.x] = m;
}

// ---------------- MFMA attention: async double-buffered K staging, single-barrier
//                  pass 1, overlapped V staging + deferred p stores in pass 2;
//                  EB consumed as bf16; tile-skip via precomputed mask ----------------
__global__ __launch_bounds__(256) void attn_mfma(
    const unsigned short* __restrict__ Qh, const unsigned short* __restrict__ Kh,
    const unsigned short* __restrict__ Vt, const unsigned short* __restrict__ EBh,
    const float* __restrict__ ebmax, const float* __restrict__ qn,
    const float* __restrict__ kmax, const unsigned int* __restrict__ skipm,
    float* __restrict__ attn_out, unsigned short* __restrict__ CTXh)
{
    // Linear LDS tiles (global_load_lds destinations must be linear) with
    // source-side XOR swizzle: LDS[row][chunk] = G[row][chunk ^ (row&7)],
    // chunks of 8 bf16 (16 B). Same pattern as the verified GEMM kernels.
    __shared__ unsigned short Ks[2][64 * 64];   // K tile double buffer (16 KB)
    __shared__ unsigned short Vts[64 * 64];     // V tile single buffer  (8 KB)
    __shared__ unsigned short Ps[4 * 16 * 72];  // per-wave P scratch    (9 KB)

    const int tid = threadIdx.x;
    const int lane = tid & 63, w = tid >> 6;
    const int quad = lane >> 4, col = lane & 15;
    const int l0 = blockIdx.x * 64;
    const int h = blockIdx.y, b = blockIdx.z;

    const unsigned int sm = skipm[(b * NUM_HEADS + h) * 32 + blockIdx.x];

    const unsigned short* kbase = Kh + ((long long)b * L_SEQ) * D_MODEL + h * DK;
    const unsigned short* vbase = Vt + ((long long)(b * NUM_HEADS + h)) * DK * L_SEQ;

    const int lr = lane >> 3, lc = lane & 7;
    const int gsw = (lc ^ lr) * 8;       // swizzled global chunk offset (shorts)

    // next active tile strictly after t (t == -1 allowed)
    auto nxt = [&](int t) -> int {
        unsigned int rem = ~sm;
        if (t >= 0) rem &= (t >= 31) ? 0u : (0xFFFFFFFFu << (t + 1));
        return rem ? (int)__builtin_ctz(rem) : -1;
    };
    const int t0 = nxt(-1);

    // ---- prologue: issue first K stage ASAP (async DMA) ----
    if (t0 >= 0) {
#pragma unroll
        for (int p = 0; p < 2; p++) {
            const int rb = w * 8 + p * 32;
            __builtin_amdgcn_global_load_lds(
                (gas_u32*)(kbase + (long long)(t0 * 64 + rb + lr) * D_MODEL + gsw),
                (las_u32*)(&Ks[0][rb * 64]), 16, 0, 0);
        }
    }

    // ---- coalesced float4 zero-fill for skipped tiles (fire-and-forget) ----
    {
        float* zbase = attn_out + (((long long)(b * NUM_HEADS + h)) * L_SEQ + l0) * L_SEQ;
        const int zc = (tid & 15) * 4;
        const int zr = tid >> 4;
        const float4 zv = {0.f, 0.f, 0.f, 0.f};
        for (int t = 0; t < 32; t++) {
            if (!(sm & (1u << t))) continue;
            float* tb = zbase + t * 64 + zc;
#pragma unroll
            for (int rr = 0; rr < 4; rr++)
                *(float4*)(tb + (long long)(rr * 16 + zr) * L_SEQ) = zv;
        }
    }

    short8 aq[2];
    {
        const unsigned short* qrow = Qh + ((long long)b * L_SEQ + l0 + w * 16 + col) * D_MODEL + h * DK;
        aq[0] = *(const short8*)(qrow + quad * 8);
        aq[1] = *(const short8*)(qrow + 32 + quad * 8);
    }

    float Mhat[4];
    {
        const float km = kmax[b * NUM_HEADS + h];
#pragma unroll
        for (int reg = 0; reg < 4; reg++) {
            int row = l0 + w * 16 + quad * 4 + reg;
            float qb = qn[((long long)(b * NUM_HEADS + h)) * L_SEQ + row];
            Mhat[reg] = ENERGY_SCALE * ebmax[(long long)b * L_SEQ + row] +
                        qb * km * 0.125f + 0.02f;
        }
    }

    const unsigned short* ebp = EBh + ((long long)b * L_SEQ + l0 + w * 16 + quad * 4) * L_SEQ + col;

    __syncthreads();   // drains prologue stage (vmcnt) + joins waves

    // ---- pass 1: rowS over active tiles, ONE barrier per tile, K prefetched ----
    float rowSacc[4] = {0.f, 0.f, 0.f, 0.f};
    int cur = 0;
    for (int t = t0; t >= 0; ) {
        const int tn = nxt(t);
        if (tn >= 0) {
#pragma unroll
            for (int p = 0; p < 2; p++) {
                const int rb = w * 8 + p * 32;
                __builtin_amdgcn_global_load_lds(
                    (gas_u32*)(kbase + (long long)(tn * 64 + rb + lr) * D_MODEL + gsw),
                    (las_u32*)(&Ks[cur ^ 1][rb * 64]), 16, 0, 0);
            }
        }
        const int m0 = t * 64;

        f32x4 acc[4];
#pragma unroll
        for (int nt = 0; nt < 4; nt++) acc[nt] = (f32x4){0.f, 0.f, 0.f, 0.f};
        __builtin_amdgcn_s_setprio(1);
#pragma unroll
        for (int nt = 0; nt < 4; nt++)
#pragma unroll
            for (int kc = 0; kc < 2; kc++) {
                short8 bk = *(const short8*)(&Ks[cur][((nt * 16 + col) << 6) +
                                                     (((quad + 4 * kc) ^ (col & 7)) << 3)]);
                acc[nt] = __builtin_amdgcn_mfma_f32_16x16x32_bf16(aq[kc], bk, acc[nt], 0, 0, 0);
            }
        __builtin_amdgcn_s_setprio(0);
#pragma unroll
        for (int nt = 0; nt < 4; nt++)
#pragma unroll
            for (int reg = 0; reg < 4; reg++) {
                float e = bf2f(ebp[(long long)reg * L_SEQ + m0 + nt * 16]);
                float s = acc[nt][reg] * 0.125f + ENERGY_SCALE * e;
                rowSacc[reg] += __expf(s - Mhat[reg]);
            }
        __syncthreads();   // next K landed; Ks[cur] free for overwrite next iter
        cur ^= 1;
        t = tn;
    }

    float invS[4];
#pragma unroll
    for (int reg = 0; reg < 4; reg++) {
        float v = rowSacc[reg];
#pragma unroll
        for (int off = 8; off > 0; off >>= 1) v += __shfl_xor(v, off, 64);
        invS[reg] = 1.f / v;
    }

    // ---- pass 2 prologue: restage first K tile ----
    cur = 0;
    if (t0 >= 0) {
#pragma unroll
        for (int p = 0; p < 2; p++) {
            const int rb = w * 8 + p * 32;
            __builtin_amdgcn_global_load_lds(
                (gas_u32*)(kbase + (long long)(t0 * 64 + rb + lr) * D_MODEL + gsw),
                (las_u32*)(&Ks[0][rb * 64]), 16, 0, 0);
        }
    }
    __syncthreads();

    // ---- pass 2: p writes + ctx = P V; V staged async under QK, p stores after barrier ----
    f32x4 ctx[4];
#pragma unroll
    for (int nt = 0; nt < 4; nt++) ctx[nt] = (f32x4){0.f, 0.f, 0.f, 0.f};

    unsigned short* Psw = Ps + w * 16 * 72;
    float* aob = attn_out + (((long long)(b * NUM_HEADS + h)) * L_SEQ + l0 + w * 16 + quad * 4) * L_SEQ + col;

    for (int t = t0; t >= 0; ) {
        const int tn = nxt(t);
        const int m0 = t * 64;

        // stage V(t) — hidden under the QK phase below
#pragma unroll
        for (int p = 0; p < 2; p++) {
            const int rb = w * 8 + p * 32;
            __builtin_amdgcn_global_load_lds(
                (gas_u32*)(vbase + (long long)(rb + lr) * L_SEQ + m0 + gsw),
                (las_u32*)(&Vts[rb * 64]), 16, 0, 0);
        }
        // prefetch next K tile
        if (tn >= 0) {
#pragma unroll
            for (int p = 0; p < 2; p++) {
                const int rb = w * 8 + p * 32;
                __builtin_amdgcn_global_load_lds(
                    (gas_u32*)(kbase + (long long)(tn * 64 + rb + lr) * D_MODEL + gsw),
                    (las_u32*)(&Ks[cur ^ 1][rb * 64]), 16, 0, 0);
            }
        }

        f32x4 acc[4];
#pragma unroll
        for (int nt = 0; nt < 4; nt++) acc[nt] = (f32x4){0.f, 0.f, 0.f, 0.f};
        __builtin_amdgcn_s_setprio(1);
#pragma unroll
        for (int nt = 0; nt < 4; nt++)
#pragma unroll
            for (int kc = 0; kc < 2; kc++) {
                short8 bk = *(const short8*)(&Ks[cur][((nt * 16 + col) << 6) +
                                                     (((quad + 4 * kc) ^ (col & 7)) << 3)]);
                acc[nt] = __builtin_amdgcn_mfma_f32_16x16x32_bf16(aq[kc], bk, acc[nt], 0, 0, 0);
            }
        __builtin_amdgcn_s_setprio(0);

        // transform scores -> normalized p in-place; write P to per-wave LDS scratch
#pragma unroll
        for (int nt = 0; nt < 4; nt++)
#pragma unroll
            for (int reg = 0; reg < 4; reg++) {
                float e = bf2f(ebp[(long long)reg * L_SEQ + m0 + nt * 16]);
                float s = acc[nt][reg] * 0.125f + ENERGY_SCALE * e;
                float p = __expf(s - Mhat[reg]) * invS[reg];
                acc[nt][reg] = p;
                Psw[(quad * 4 + reg) * 72 + nt * 16 + col] = f2bf(p);
            }
        __syncthreads();   // V tile landed (and next K issued early)

        // global p stores issued now — they drain during the PV phase
#pragma unroll
        for (int nt = 0; nt < 4; nt++)
#pragma unroll
            for (int reg = 0; reg < 4; reg++)
                aob[(long long)reg * L_SEQ + m0 + nt * 16] = acc[nt][reg];

        short8 ap[2];
#pragma unroll
        for (int kc = 0; kc < 2; kc++)
            ap[kc] = *(const short8*)(Psw + col * 72 + quad * 8 + kc * 32);
        __builtin_amdgcn_s_setprio(1);
#pragma unroll
        for (int nt = 0; nt < 4; nt++)
#pragma unroll
            for (int kc = 0; kc < 2; kc++) {
                short8 bv = *(const short8*)(&Vts[((nt * 16 + col) << 6) +
                                                  (((quad + 4 * kc) ^ (col & 7)) << 3)]);
                ctx[nt] = __builtin_amdgcn_mfma_f32_16x16x32_bf16(ap[kc], bv, ctx[nt], 0, 0, 0);
            }
        __builtin_amdgcn_s_setprio(0);
        __syncthreads();   // protect Vts (and Ps) against next-iter overwrite
        cur ^= 1;
        t = tn;
    }

#pragma unroll
    for (int nt = 0; nt < 4; nt++)
#pragma unroll
        for (int reg = 0; reg < 4; reg++)
            CTXh[((long long)b * L_SEQ + l0 + w * 16 + quad * 4 + reg) * D_MODEL + h * DK + nt * 16 + col] =
                f2bf(ctx[nt][reg]);
}

extern "C" void kernel_launch(void* const* d_in, const int* in_sizes, int n_in,
                              void* d_out, int out_size, void* d_ws, size_t ws_size,
                              hipStream_t stream) {
    const float* x    = (const float*)d_in[0];
    const float* wq   = (const float*)d_in[1];
    const float* wk   = (const float*)d_in[2];
    const float* wv   = (const float*)d_in[3];
    const float* wo_w = (const float*)d_in[4];
    const float* wo_b = (const float*)d_in[5];
    const float* ep_w = (const float*)d_in[6];
    const float* ep_b = (const float*)d_in[7];
    const float* en_g = (const float*)d_in[8];
    const float* en_b = (const float*)d_in[9];
    const float* ln_g = (const float*)d_in[10];
    const float* ln_b = (const float*)d_in[11];

    float* out_final = (float*)d_out;
    float* attn_out  = out_final + (long long)BATCH * L_SEQ * D_MODEL;

    const long long MD = (long long)BATCH * L_SEQ * D_MODEL;   // 4,194,304
    const long long WN = (long long)D_MODEL * D_MODEL;         // 1,048,576
    const long long BH = (long long)BATCH * NUM_HEADS;
    const long long LL = (long long)BATCH * L_SEQ * L_SEQ;     // 8,388,608

    unsigned short* EBh = (unsigned short*)d_ws;               // [B,L,L] bf16
    float* EP = (float*)(EBh + LL);                            // MD fp32 (also OUT)
    unsigned short* Xh   = (unsigned short*)(EP + MD);
    unsigned short* Qh   = Xh + MD;
    unsigned short* Kh   = Qh + MD;
    unsigned short* Vf   = Kh + MD;
    unsigned short* Vt   = Vf + MD;
    unsigned short* EFh  = Vt + MD;
    unsigned short* CTXh = EFh + MD;
    unsigned short* wqh  = CTXh + MD;
    unsigned short* wkh  = wqh + WN;
    unsigned short* wvh  = wkh + WN;
    unsigned short* eph  = wvh + WN;
    unsigned short* woh  = eph + WN;
    float* ebmax  = (float*)(woh + WN);                        // B*L
    float* qn     = ebmax + (long long)BATCH * L_SEQ;          // B*H*L
    float* kn     = qn + BH * L_SEQ;                           // B*H*L
    float* kmax   = kn + BH * L_SEQ;                           // B*H
    float* ktmax  = kmax + BH;                                 // B*H*32
    float* ebtmax = ktmax + BH * 32;                           // B*L*32
    unsigned int* skipm = (unsigned int*)(ebtmax + (long long)BATCH * L_SEQ * 32); // B*H*32
    float* OUT = EP;                                           // EP dead after ln

    const int M = BATCH * L_SEQ;                               // 4096
    dim3 blk(256);

    cvt6<<<dim3((unsigned)(MD / 1024), 6), blk, 0, stream>>>(
        x, wq, wk, wv, ep_w, wo_w, Xh, wqh, wkh, wvh, eph, woh,
        MD, WN, WN, WN, WN, WN);

    proj_gemm<<<dim3(D_MODEL / 128, M / 128, 4), blk, 0, stream>>>(
        Xh, wqh, wkh, wvh, eph, ep_b, Qh, Kh, Vf, EP);

    ln_rows<<<dim3(M), blk, 0, stream>>>(EP, nullptr, en_g, en_b, nullptr, EFh);

    gemm_bf16<<<dim3(L_SEQ / 128, L_SEQ / 128, BATCH), blk, 0, stream>>>(
        EFh, EFh, nullptr, nullptr, EBh, L_SEQ, D_MODEL,
        (long long)L_SEQ * D_MODEL, (long long)L_SEQ * D_MODEL,
        (long long)L_SEQ * L_SEQ);

    qk_stats<<<dim3(L_SEQ / 64, NUM_HEADS, BATCH), blk, 0, stream>>>(Qh, Kh, qn, kn);
    kstats2<<<dim3((unsigned)BH), blk, 0, stream>>>(kn, kmax, ktmax);
    eb_stats<<<dim3(M), blk, 0, stream>>>(EBh, ebmax, ebtmax);
    skip_mask<<<dim3(L_SEQ / 64, NUM_HEADS, BATCH), dim3(64), 0, stream>>>(
        ebmax, ebtmax, qn, kmax, ktmax, skipm);

    transpose_v<<<dim3(L_SEQ / 64, NUM_HEADS, BATCH), blk, 0, stream>>>(Vf, Vt);

    attn_mfma<<<dim3(L_SEQ / 64, NUM_HEADS, BATCH), blk, 0, stream>>>(
        Qh, Kh, Vt, EBh, ebmax, qn, kmax, skipm, attn_out, CTXh);

    gemm_bf16<<<dim3(D_MODEL / 128, M / 128, 1), blk, 0, stream>>>(
        CTXh, woh, wo_b, OUT, nullptr, D_MODEL, D_MODEL, 0, 0, 0);

    ln_rows<<<dim3(M), blk, 0, stream>>>(OUT, x, ln_g, ln_b, out_final, nullptr);
}

// Round 5
// 743.014 us; speedup vs baseline: 1.2521x; 1.0084x over previous
//
#include <hip/hip_runtime.h>
#include <math.h>

#define D_MODEL 1024
#define NUM_HEADS 16
#define DK 64
#define L_SEQ 2048
#define BATCH 2
#define LN_EPS 1e-5f
#define ENERGY_SCALE 0.1f

typedef __attribute__((ext_vector_type(8))) short short8;
typedef __attribute__((ext_vector_type(4))) float f32x4;
typedef __attribute__((address_space(1))) const unsigned int gas_u32;
typedef __attribute__((address_space(3))) unsigned int las_u32;

__device__ __forceinline__ float waveReduceSum(float v) {
#pragma unroll
    for (int off = 32; off > 0; off >>= 1) v += __shfl_xor(v, off, 64);
    return v;
}

__device__ __forceinline__ unsigned short f2bf(float f) {
    unsigned int u = __float_as_uint(f);
    u += 0x7fff + ((u >> 16) & 1);          // round-to-nearest-even
    return (unsigned short)(u >> 16);
}
__device__ __forceinline__ float bf2f(unsigned short u) {
    return __uint_as_float((unsigned int)u << 16);
}

// ---------------- fp32 -> bf16 convert, 6 matrices in one launch ----------------
__global__ __launch_bounds__(256) void cvt6(
    const float* s0, const float* s1, const float* s2,
    const float* s3, const float* s4, const float* s5,
    unsigned short* d0, unsigned short* d1, unsigned short* d2,
    unsigned short* d3, unsigned short* d4, unsigned short* d5,
    long long n0, long long n1, long long n2, long long n3, long long n4, long long n5)
{
    const float* s; unsigned short* d; long long n;
    switch (blockIdx.y) {
        case 0: s = s0; d = d0; n = n0; break;
        case 1: s = s1; d = d1; n = n1; break;
        case 2: s = s2; d = d2; n = n2; break;
        case 3: s = s3; d = d3; n = n3; break;
        case 4: s = s4; d = d4; n = n4; break;
        default: s = s5; d = d5; n = n5; break;
    }
    long long i = ((long long)blockIdx.x * 256 + threadIdx.x) * 4;
    if (i >= n) return;
    float4 v = *(const float4*)(s + i);
    ushort4 o;
    o.x = f2bf(v.x); o.y = f2bf(v.y); o.z = f2bf(v.z); o.w = f2bf(v.w);
    *(ushort4*)(d + i) = o;
}

// ---------------- bf16 MFMA GEMM with global_load_lds; optional fused
//                  per-(row, 64-col-tile) max epilogue (for EB stats) ----------------
__global__ __launch_bounds__(256) void gemm_bf16(
    const unsigned short* __restrict__ A, const unsigned short* __restrict__ B,
    const float* __restrict__ bias, float* __restrict__ Cf, unsigned short* __restrict__ Ch,
    int N, int K, long long sA, long long sB, long long sC,
    float* __restrict__ ebtmax)
{
    A += (long long)blockIdx.z * sA;
    B += (long long)blockIdx.z * sB;
    __shared__ unsigned short As[128 * 64];
    __shared__ unsigned short Bs[128 * 64];
    const int tid = threadIdx.x;
    const int lane = tid & 63, w = tid >> 6;
    const int quad = lane >> 4, col = lane & 15;
    const int wm = w & 1, wn = w >> 1;
    const int row0 = blockIdx.y * 128, col0 = blockIdx.x * 128;

    const int lr = lane >> 3, lc = lane & 7;
    const int gcs = (lc ^ lr) * 8;

    f32x4 acc[4][4];
#pragma unroll
    for (int mt = 0; mt < 4; mt++)
#pragma unroll
        for (int nt = 0; nt < 4; nt++) acc[mt][nt] = (f32x4){0.f, 0.f, 0.f, 0.f};

    for (int k0 = 0; k0 < K; k0 += 64) {
        __syncthreads();
#pragma unroll
        for (int p = 0; p < 4; p++) {
            const int rb = w * 32 + p * 8;
            __builtin_amdgcn_global_load_lds(
                (gas_u32*)(A + (long long)(row0 + rb + lr) * K + k0 + gcs),
                (las_u32*)(As + rb * 64), 16, 0, 0);
            __builtin_amdgcn_global_load_lds(
                (gas_u32*)(B + (long long)(col0 + rb + lr) * K + k0 + gcs),
                (las_u32*)(Bs + rb * 64), 16, 0, 0);
        }
        __syncthreads();
#pragma unroll
        for (int kc = 0; kc < 2; kc++) {
            const int csw = ((quad + 4 * kc) ^ (col & 7)) * 8;
            short8 af[4], bfr[4];
#pragma unroll
            for (int mt = 0; mt < 4; mt++)
                af[mt] = *(const short8*)(As + (wm * 64 + mt * 16 + col) * 64 + csw);
#pragma unroll
            for (int nt = 0; nt < 4; nt++)
                bfr[nt] = *(const short8*)(Bs + (wn * 64 + nt * 16 + col) * 64 + csw);
#pragma unroll
            for (int mt = 0; mt < 4; mt++)
#pragma unroll
                for (int nt = 0; nt < 4; nt++)
                    acc[mt][nt] = __builtin_amdgcn_mfma_f32_16x16x32_bf16(af[mt], bfr[nt], acc[mt][nt], 0, 0, 0);
        }
    }

#pragma unroll
    for (int mt = 0; mt < 4; mt++)
#pragma unroll
        for (int nt = 0; nt < 4; nt++)
#pragma unroll
            for (int reg = 0; reg < 4; reg++) {
                long long row = row0 + wm * 64 + mt * 16 + quad * 4 + reg;
                int c = col0 + wn * 64 + nt * 16 + col;
                float v = acc[mt][nt][reg];
                if (bias) v += bias[c];
                if (Cf) Cf[blockIdx.z * sC + row * N + c] = v;
                else    Ch[blockIdx.z * sC + row * N + c] = f2bf(v);
            }

    // fused EB per-(row, col-tile) max: each wave's 64 cols = one 64-col tile
    if (ebtmax) {
        const int tcol = blockIdx.x * 2 + wn;
#pragma unroll
        for (int mt = 0; mt < 4; mt++) {
            float mx[4];
#pragma unroll
            for (int reg = 0; reg < 4; reg++) mx[reg] = acc[mt][0][reg];
#pragma unroll
            for (int nt = 1; nt < 4; nt++)
#pragma unroll
                for (int reg = 0; reg < 4; reg++)
                    mx[reg] = fmaxf(mx[reg], acc[mt][nt][reg]);
#pragma unroll
            for (int off = 8; off > 0; off >>= 1)
#pragma unroll
                for (int reg = 0; reg < 4; reg++)
                    mx[reg] = fmaxf(mx[reg], __shfl_xor(mx[reg], off, 64));
            if (col == 0) {
                long long rowg = (long long)blockIdx.z * L_SEQ + row0 + wm * 64 + mt * 16 + quad * 4;
#pragma unroll
                for (int reg = 0; reg < 4; reg++)
                    ebtmax[(rowg + reg) * 32 + tcol] = bf2f(f2bf(mx[reg]));  // bound on rounded values
            }
        }
    }
}

// ---------------- fused projections with global_load_lds + fused q/k row norms ----------------
__global__ __launch_bounds__(256) void proj_gemm(
    const unsigned short* __restrict__ Xh,
    const unsigned short* __restrict__ wqh, const unsigned short* __restrict__ wkh,
    const unsigned short* __restrict__ wvh, const unsigned short* __restrict__ eph,
    const float* __restrict__ ep_b,
    unsigned short* __restrict__ Qh, unsigned short* __restrict__ Kh,
    unsigned short* __restrict__ Vf, float* __restrict__ EP,
    float* __restrict__ qn, float* __restrict__ kn)
{
    const unsigned short* B;
    switch (blockIdx.z) {
        case 0: B = wqh; break;
        case 1: B = wkh; break;
        case 2: B = wvh; break;
        default: B = eph; break;
    }
    __shared__ unsigned short As[128 * 64];
    __shared__ unsigned short Bs[128 * 64];
    const int tid = threadIdx.x;
    const int lane = tid & 63, w = tid >> 6;
    const int quad = lane >> 4, col = lane & 15;
    const int wm = w & 1, wn = w >> 1;
    const int row0 = blockIdx.y * 128, col0 = blockIdx.x * 128;
    const int K = D_MODEL, N = D_MODEL;

    const int lr = lane >> 3, lc = lane & 7;
    const int gcs = (lc ^ lr) * 8;

    f32x4 acc[4][4];
#pragma unroll
    for (int mt = 0; mt < 4; mt++)
#pragma unroll
        for (int nt = 0; nt < 4; nt++) acc[mt][nt] = (f32x4){0.f, 0.f, 0.f, 0.f};

    for (int k0 = 0; k0 < K; k0 += 64) {
        __syncthreads();
#pragma unroll
        for (int p = 0; p < 4; p++) {
            const int rb = w * 32 + p * 8;
            __builtin_amdgcn_global_load_lds(
                (gas_u32*)(Xh + (long long)(row0 + rb + lr) * K + k0 + gcs),
                (las_u32*)(As + rb * 64), 16, 0, 0);
            __builtin_amdgcn_global_load_lds(
                (gas_u32*)(B + (long long)(col0 + rb + lr) * K + k0 + gcs),
                (las_u32*)(Bs + rb * 64), 16, 0, 0);
        }
        __syncthreads();
#pragma unroll
        for (int kc = 0; kc < 2; kc++) {
            const int csw = ((quad + 4 * kc) ^ (col & 7)) * 8;
            short8 af[4], bfr[4];
#pragma unroll
            for (int mt = 0; mt < 4; mt++)
                af[mt] = *(const short8*)(As + (wm * 64 + mt * 16 + col) * 64 + csw);
#pragma unroll
            for (int nt = 0; nt < 4; nt++)
                bfr[nt] = *(const short8*)(Bs + (wn * 64 + nt * 16 + col) * 64 + csw);
#pragma unroll
            for (int mt = 0; mt < 4; mt++)
#pragma unroll
                for (int nt = 0; nt < 4; nt++)
                    acc[mt][nt] = __builtin_amdgcn_mfma_f32_16x16x32_bf16(af[mt], bfr[nt], acc[mt][nt], 0, 0, 0);
        }
    }

    unsigned short* Hout = (blockIdx.z == 0) ? Qh : (blockIdx.z == 1) ? Kh : Vf;
#pragma unroll
    for (int mt = 0; mt < 4; mt++)
#pragma unroll
        for (int nt = 0; nt < 4; nt++)
#pragma unroll
            for (int reg = 0; reg < 4; reg++) {
                long long row = row0 + wm * 64 + mt * 16 + quad * 4 + reg;
                int c = col0 + wn * 64 + nt * 16 + col;
                float v = acc[mt][nt][reg];
                if (blockIdx.z == 3) EP[row * N + c] = v + ep_b[c];
                else                 Hout[row * N + c] = f2bf(v);
            }

    // fused q/k row-norms: each wave's 64 cols align exactly with one head
    if (blockIdx.z <= 1) {
        float* dst = (blockIdx.z == 0) ? qn : kn;
        const int hh = blockIdx.x * 2 + wn;
#pragma unroll
        for (int mt = 0; mt < 4; mt++) {
            float s2[4];
#pragma unroll
            for (int reg = 0; reg < 4; reg++) s2[reg] = 0.f;
#pragma unroll
            for (int nt = 0; nt < 4; nt++)
#pragma unroll
                for (int reg = 0; reg < 4; reg++)
                    s2[reg] += acc[mt][nt][reg] * acc[mt][nt][reg];
#pragma unroll
            for (int off = 8; off > 0; off >>= 1)
#pragma unroll
                for (int reg = 0; reg < 4; reg++)
                    s2[reg] += __shfl_xor(s2[reg], off, 64);
            if (col == 0) {
                int row = row0 + wm * 64 + mt * 16 + quad * 4;
                int bb = row >> 11, l = row & (L_SEQ - 1);
                float4 o;
                o.x = sqrtf(s2[0]); o.y = sqrtf(s2[1]);
                o.z = sqrtf(s2[2]); o.w = sqrtf(s2[3]);
                *(float4*)(dst + ((long long)(bb * NUM_HEADS + hh)) * L_SEQ + l) = o;
            }
        }
    }
}

// ---------------- LayerNorm rows ----------------
__global__ __launch_bounds__(256) void ln_rows(
    const float* __restrict__ in, const float* __restrict__ res,
    const float* __restrict__ g, const float* __restrict__ bta,
    float* __restrict__ outf, unsigned short* __restrict__ outh)
{
    const long long row = blockIdx.x;
    const float* ip = in + row * D_MODEL;
    const float* rp = res ? res + row * D_MODEL : nullptr;
    const int tid = threadIdx.x;
    float vals[4];
    float s = 0.f, ss = 0.f;
#pragma unroll
    for (int j = 0; j < 4; j++) {
        int idx = tid + j * 256;
        float v = ip[idx];
        if (rp) v += rp[idx];
        vals[j] = v; s += v; ss += v * v;
    }
    __shared__ float sred[4], ssred[4];
    s = waveReduceSum(s); ss = waveReduceSum(ss);
    int wave = tid >> 6, lane = tid & 63;
    if (lane == 0) { sred[wave] = s; ssred[wave] = ss; }
    __syncthreads();
    float ts = sred[0] + sred[1] + sred[2] + sred[3];
    float tss = ssred[0] + ssred[1] + ssred[2] + ssred[3];
    float mu = ts * (1.f / D_MODEL);
    float var = tss * (1.f / D_MODEL) - mu * mu;
    float rs = rsqrtf(var + LN_EPS);
#pragma unroll
    for (int j = 0; j < 4; j++) {
        int idx = tid + j * 256;
        float o = (vals[j] - mu) * rs * g[idx] + bta[idx];
        if (outf) __builtin_nontemporal_store(o, outf + row * D_MODEL + idx);
        else      outh[row * D_MODEL + idx] = f2bf(o);
    }
}

// ---------------- V transpose ----------------
__global__ __launch_bounds__(256) void transpose_v(
    const unsigned short* __restrict__ V, unsigned short* __restrict__ Vt)
{
    const int m0 = blockIdx.x * 64, h = blockIdx.y, b = blockIdx.z;
    __shared__ unsigned int t[64][65];
    const int tid = threadIdx.x;
    {
        int r = tid >> 4, c4 = (tid & 15) * 4;
#pragma unroll
        for (int i = 0; i < 4; i++) {
            int row = r + i * 16;
            ushort4 v = *(const ushort4*)(V + ((long long)b * L_SEQ + m0 + row) * D_MODEL + h * DK + c4);
            t[row][c4] = v.x; t[row][c4 + 1] = v.y; t[row][c4 + 2] = v.z; t[row][c4 + 3] = v.w;
        }
    }
    __syncthreads();
    const int lane = tid & 63, wv = tid >> 6;
#pragma unroll
    for (int i = 0; i < 16; i++) {
        int d = wv * 16 + i;
        Vt[(((long long)(b * NUM_HEADS + h)) * DK + d) * L_SEQ + m0 + lane] = (unsigned short)t[lane][d];
    }
}

// ---------------- stats: per-(b,h) k-norm global + per-tile max ----------------
__global__ __launch_bounds__(256) void kstats2(
    const float* __restrict__ kn, float* __restrict__ kmax, float* __restrict__ ktmax)
{
    const long long bh = blockIdx.x;
    const float* p = kn + bh * L_SEQ;
    const int tid = threadIdx.x;
    float4 a = *(const float4*)(p + tid * 8);
    float4 c = *(const float4*)(p + tid * 8 + 4);
    float m = fmaxf(fmaxf(fmaxf(a.x, a.y), fmaxf(a.z, a.w)),
                    fmaxf(fmaxf(c.x, c.y), fmaxf(c.z, c.w)));
    m = fmaxf(m, __shfl_xor(m, 1, 64));
    m = fmaxf(m, __shfl_xor(m, 2, 64));
    m = fmaxf(m, __shfl_xor(m, 4, 64));
    if ((tid & 7) == 0) ktmax[bh * 32 + (tid >> 3)] = m;
    m = fmaxf(m, __shfl_xor(m, 8, 64));
    m = fmaxf(m, __shfl_xor(m, 16, 64));
    m = fmaxf(m, __shfl_xor(m, 32, 64));
    __shared__ float red[4];
    if ((tid & 63) == 0) red[tid >> 6] = m;
    __syncthreads();
    if (tid == 0)
        kmax[bh] = fmaxf(fmaxf(red[0], red[1]), fmaxf(red[2], red[3]));
}

// ---------------- skip mask (also derives + stores ebmax from ebtmax) ----------------
__global__ __launch_bounds__(64) void skip_mask(
    const float* __restrict__ ebtmax, const float* __restrict__ qn,
    const float* __restrict__ kmax, const float* __restrict__ ktmax,
    unsigned int* __restrict__ skipm, float* __restrict__ ebmax)
{
    const int l0 = blockIdx.x * 64, h = blockIdx.y, b = blockIdx.z;
    const int tid = threadIdx.x;
    const int row = l0 + tid;
    const int bh = b * NUM_HEADS + h;
    const float* ebt = ebtmax + ((long long)b * L_SEQ + row) * 32;
    float ebr[32];
#pragma unroll
    for (int t = 0; t < 32; t++) ebr[t] = ebt[t];
    float mx = ebr[0];
#pragma unroll
    for (int t = 1; t < 32; t++) mx = fmaxf(mx, ebr[t]);
    if (blockIdx.y == 0) ebmax[(long long)b * L_SEQ + row] = mx;

    float q = qn[(long long)bh * L_SEQ + row];
    float Mh = ENERGY_SCALE * mx + q * kmax[bh] * 0.125f + 0.02f;
    const float* ktm = ktmax + bh * 32;
    unsigned int m = 0;
#pragma unroll
    for (int t = 0; t < 32; t++) {
        float ub = ENERGY_SCALE * ebr[t] + q * ktm[t] * 0.125f;
        unsigned long long bal = __ballot(ub < Mh - 45.0f);
        if (bal == ~0ull) m |= (1u << t);
    }
    if (tid == 0) skipm[bh * 32 + blockIdx.x] = m;
}

// ---------------- MFMA attention: async double-buffered K staging, single-barrier
//                  pass 1, overlapped V staging + deferred p stores in pass 2;
//                  EB consumed as bf16; tile-skip via precomputed mask;
//                  nontemporal stores for attn_out (never re-read) ----------------
__global__ __launch_bounds__(256) void attn_mfma(
    const unsigned short* __restrict__ Qh, const unsigned short* __restrict__ Kh,
    const unsigned short* __restrict__ Vt, const unsigned short* __restrict__ EBh,
    const float* __restrict__ ebmax, const float* __restrict__ qn,
    const float* __restrict__ kmax, const unsigned int* __restrict__ skipm,
    float* __restrict__ attn_out, unsigned short* __restrict__ CTXh)
{
    __shared__ unsigned short Ks[2][64 * 64];   // K tile double buffer (16 KB)
    __shared__ unsigned short Vts[64 * 64];     // V tile single buffer  (8 KB)
    __shared__ unsigned short Ps[4 * 16 * 72];  // per-wave P scratch    (9 KB)

    const int tid = threadIdx.x;
    const int lane = tid & 63, w = tid >> 6;
    const int quad = lane >> 4, col = lane & 15;
    const int l0 = blockIdx.x * 64;
    const int h = blockIdx.y, b = blockIdx.z;

    const unsigned int sm = skipm[(b * NUM_HEADS + h) * 32 + blockIdx.x];

    const unsigned short* kbase = Kh + ((long long)b * L_SEQ) * D_MODEL + h * DK;
    const unsigned short* vbase = Vt + ((long long)(b * NUM_HEADS + h)) * DK * L_SEQ;

    const int lr = lane >> 3, lc = lane & 7;
    const int gsw = (lc ^ lr) * 8;       // swizzled global chunk offset (shorts)

    auto nxt = [&](int t) -> int {
        unsigned int rem = ~sm;
        if (t >= 0) rem &= (t >= 31) ? 0u : (0xFFFFFFFFu << (t + 1));
        return rem ? (int)__builtin_ctz(rem) : -1;
    };
    const int t0 = nxt(-1);

    // ---- prologue: issue first K stage ASAP (async DMA) ----
    if (t0 >= 0) {
#pragma unroll
        for (int p = 0; p < 2; p++) {
            const int rb = w * 8 + p * 32;
            __builtin_amdgcn_global_load_lds(
                (gas_u32*)(kbase + (long long)(t0 * 64 + rb + lr) * D_MODEL + gsw),
                (las_u32*)(&Ks[0][rb * 64]), 16, 0, 0);
        }
    }

    // ---- coalesced zero-fill for skipped tiles (nontemporal, fire-and-forget) ----
    {
        float* zbase = attn_out + (((long long)(b * NUM_HEADS + h)) * L_SEQ + l0) * L_SEQ;
        const int zc = (tid & 15) * 4;
        const int zr = tid >> 4;
        const f32x4 zv = {0.f, 0.f, 0.f, 0.f};
        for (int t = 0; t < 32; t++) {
            if (!(sm & (1u << t))) continue;
            float* tb = zbase + t * 64 + zc;
#pragma unroll
            for (int rr = 0; rr < 4; rr++)
                __builtin_nontemporal_store(zv, (f32x4*)(tb + (long long)(rr * 16 + zr) * L_SEQ));
        }
    }

    short8 aq[2];
    {
        const unsigned short* qrow = Qh + ((long long)b * L_SEQ + l0 + w * 16 + col) * D_MODEL + h * DK;
        aq[0] = *(const short8*)(qrow + quad * 8);
        aq[1] = *(const short8*)(qrow + 32 + quad * 8);
    }

    float Mhat[4];
    {
        const float km = kmax[b * NUM_HEADS + h];
#pragma unroll
        for (int reg = 0; reg < 4; reg++) {
            int row = l0 + w * 16 + quad * 4 + reg;
            float qb = qn[((long long)(b * NUM_HEADS + h)) * L_SEQ + row];
            Mhat[reg] = ENERGY_SCALE * ebmax[(long long)b * L_SEQ + row] +
                        qb * km * 0.125f + 0.02f;
        }
    }

    const unsigned short* ebp = EBh + ((long long)b * L_SEQ + l0 + w * 16 + quad * 4) * L_SEQ + col;

    __syncthreads();   // drains prologue stage (vmcnt) + joins waves

    // ---- pass 1: rowS over active tiles, ONE barrier per tile, K prefetched ----
    float rowSacc[4] = {0.f, 0.f, 0.f, 0.f};
    int cur = 0;
    for (int t = t0; t >= 0; ) {
        const int tn = nxt(t);
        if (tn >= 0) {
#pragma unroll
            for (int p = 0; p < 2; p++) {
                const int rb = w * 8 + p * 32;
                __builtin_amdgcn_global_load_lds(
                    (gas_u32*)(kbase + (long long)(tn * 64 + rb + lr) * D_MODEL + gsw),
                    (las_u32*)(&Ks[cur ^ 1][rb * 64]), 16, 0, 0);
            }
        }
        const int m0 = t * 64;

        f32x4 acc[4];
#pragma unroll
        for (int nt = 0; nt < 4; nt++) acc[nt] = (f32x4){0.f, 0.f, 0.f, 0.f};
        __builtin_amdgcn_s_setprio(1);
#pragma unroll
        for (int nt = 0; nt < 4; nt++)
#pragma unroll
            for (int kc = 0; kc < 2; kc++) {
                short8 bk = *(const short8*)(&Ks[cur][((nt * 16 + col) << 6) +
                                                     (((quad + 4 * kc) ^ (col & 7)) << 3)]);
                acc[nt] = __builtin_amdgcn_mfma_f32_16x16x32_bf16(aq[kc], bk, acc[nt], 0, 0, 0);
            }
        __builtin_amdgcn_s_setprio(0);
#pragma unroll
        for (int nt = 0; nt < 4; nt++)
#pragma unroll
            for (int reg = 0; reg < 4; reg++) {
                float e = bf2f(ebp[(long long)reg * L_SEQ + m0 + nt * 16]);
                float s = acc[nt][reg] * 0.125f + ENERGY_SCALE * e;
                rowSacc[reg] += __expf(s - Mhat[reg]);
            }
        __syncthreads();   // next K landed; Ks[cur] free for overwrite next iter
        cur ^= 1;
        t = tn;
    }

    float invS[4];
#pragma unroll
    for (int reg = 0; reg < 4; reg++) {
        float v = rowSacc[reg];
#pragma unroll
        for (int off = 8; off > 0; off >>= 1) v += __shfl_xor(v, off, 64);
        invS[reg] = 1.f / v;
    }

    // ---- pass 2 prologue: restage first K tile ----
    cur = 0;
    if (t0 >= 0) {
#pragma unroll
        for (int p = 0; p < 2; p++) {
            const int rb = w * 8 + p * 32;
            __builtin_amdgcn_global_load_lds(
                (gas_u32*)(kbase + (long long)(t0 * 64 + rb + lr) * D_MODEL + gsw),
                (las_u32*)(&Ks[0][rb * 64]), 16, 0, 0);
        }
    }
    __syncthreads();

    // ---- pass 2: p writes + ctx = P V; V staged async under QK, p stores after barrier ----
    f32x4 ctx[4];
#pragma unroll
    for (int nt = 0; nt < 4; nt++) ctx[nt] = (f32x4){0.f, 0.f, 0.f, 0.f};

    unsigned short* Psw = Ps + w * 16 * 72;
    float* aob = attn_out + (((long long)(b * NUM_HEADS + h)) * L_SEQ + l0 + w * 16 + quad * 4) * L_SEQ + col;

    for (int t = t0; t >= 0; ) {
        const int tn = nxt(t);
        const int m0 = t * 64;

        // stage V(t) — hidden under the QK phase below
#pragma unroll
        for (int p = 0; p < 2; p++) {
            const int rb = w * 8 + p * 32;
            __builtin_amdgcn_global_load_lds(
                (gas_u32*)(vbase + (long long)(rb + lr) * L_SEQ + m0 + gsw),
                (las_u32*)(&Vts[rb * 64]), 16, 0, 0);
        }
        // prefetch next K tile
        if (tn >= 0) {
#pragma unroll
            for (int p = 0; p < 2; p++) {
                const int rb = w * 8 + p * 32;
                __builtin_amdgcn_global_load_lds(
                    (gas_u32*)(kbase + (long long)(tn * 64 + rb + lr) * D_MODEL + gsw),
                    (las_u32*)(&Ks[cur ^ 1][rb * 64]), 16, 0, 0);
            }
        }

        f32x4 acc[4];
#pragma unroll
        for (int nt = 0; nt < 4; nt++) acc[nt] = (f32x4){0.f, 0.f, 0.f, 0.f};
        __builtin_amdgcn_s_setprio(1);
#pragma unroll
        for (int nt = 0; nt < 4; nt++)
#pragma unroll
            for (int kc = 0; kc < 2; kc++) {
                short8 bk = *(const short8*)(&Ks[cur][((nt * 16 + col) << 6) +
                                                     (((quad + 4 * kc) ^ (col & 7)) << 3)]);
                acc[nt] = __builtin_amdgcn_mfma_f32_16x16x32_bf16(aq[kc], bk, acc[nt], 0, 0, 0);
            }
        __builtin_amdgcn_s_setprio(0);

        // transform scores -> normalized p in-place; write P to per-wave LDS scratch
#pragma unroll
        for (int nt = 0; nt < 4; nt++)
#pragma unroll
            for (int reg = 0; reg < 4; reg++) {
                float e = bf2f(ebp[(long long)reg * L_SEQ + m0 + nt * 16]);
                float s = acc[nt][reg] * 0.125f + ENERGY_SCALE * e;
                float p = __expf(s - Mhat[reg]) * invS[reg];
                acc[nt][reg] = p;
                Psw[(quad * 4 + reg) * 72 + nt * 16 + col] = f2bf(p);
            }
        __syncthreads();   // V tile landed (and next K issued early)

        // global p stores issued now (nontemporal) — drain during the PV phase
#pragma unroll
        for (int nt = 0; nt < 4; nt++)
#pragma unroll
            for (int reg = 0; reg < 4; reg++)
                __builtin_nontemporal_store(acc[nt][reg],
                    aob + (long long)reg * L_SEQ + m0 + nt * 16);

        short8 ap[2];
#pragma unroll
        for (int kc = 0; kc < 2; kc++)
            ap[kc] = *(const short8*)(Psw + col * 72 + quad * 8 + kc * 32);
        __builtin_amdgcn_s_setprio(1);
#pragma unroll
        for (int nt = 0; nt < 4; nt++)
#pragma unroll
            for (int kc = 0; kc < 2; kc++) {
                short8 bv = *(const short8*)(&Vts[((nt * 16 + col) << 6) +
                                                  (((quad + 4 * kc) ^ (col & 7)) << 3)]);
                ctx[nt] = __builtin_amdgcn_mfma_f32_16x16x32_bf16(ap[kc], bv, ctx[nt], 0, 0, 0);
            }
        __builtin_amdgcn_s_setprio(0);
        __syncthreads();   // protect Vts (and Ps) against next-iter overwrite
        cur ^= 1;
        t = tn;
    }

#pragma unroll
    for (int nt = 0; nt < 4; nt++)
#pragma unroll
        for (int reg = 0; reg < 4; reg++)
            CTXh[((long long)b * L_SEQ + l0 + w * 16 + quad * 4 + reg) * D_MODEL + h * DK + nt * 16 + col] =
                f2bf(ctx[nt][reg]);
}

extern "C" void kernel_launch(void* const* d_in, const int* in_sizes, int n_in,
                              void* d_out, int out_size, void* d_ws, size_t ws_size,
                              hipStream_t stream) {
    const float* x    = (const float*)d_in[0];
    const float* wq   = (const float*)d_in[1];
    const float* wk   = (const float*)d_in[2];
    const float* wv   = (const float*)d_in[3];
    const float* wo_w = (const float*)d_in[4];
    const float* wo_b = (const float*)d_in[5];
    const float* ep_w = (const float*)d_in[6];
    const float* ep_b = (const float*)d_in[7];
    const float* en_g = (const float*)d_in[8];
    const float* en_b = (const float*)d_in[9];
    const float* ln_g = (const float*)d_in[10];
    const float* ln_b = (const float*)d_in[11];

    float* out_final = (float*)d_out;
    float* attn_out  = out_final + (long long)BATCH * L_SEQ * D_MODEL;

    const long long MD = (long long)BATCH * L_SEQ * D_MODEL;   // 4,194,304
    const long long WN = (long long)D_MODEL * D_MODEL;         // 1,048,576
    const long long BH = (long long)BATCH * NUM_HEADS;
    const long long LL = (long long)BATCH * L_SEQ * L_SEQ;     // 8,388,608

    unsigned short* EBh = (unsigned short*)d_ws;               // [B,L,L] bf16
    float* EP = (float*)(EBh + LL);                            // MD fp32 (also OUT)
    unsigned short* Xh   = (unsigned short*)(EP + MD);
    unsigned short* Qh   = Xh + MD;
    unsigned short* Kh   = Qh + MD;
    unsigned short* Vf   = Kh + MD;
    unsigned short* Vt   = Vf + MD;
    unsigned short* EFh  = Vt + MD;
    unsigned short* CTXh = EFh + MD;
    unsigned short* wqh  = CTXh + MD;
    unsigned short* wkh  = wqh + WN;
    unsigned short* wvh  = wkh + WN;
    unsigned short* eph  = wvh + WN;
    unsigned short* woh  = eph + WN;
    float* ebmax  = (float*)(woh + WN);                        // B*L
    float* qn     = ebmax + (long long)BATCH * L_SEQ;          // B*H*L
    float* kn     = qn + BH * L_SEQ;                           // B*H*L
    float* kmax   = kn + BH * L_SEQ;                           // B*H
    float* ktmax  = kmax + BH;                                 // B*H*32
    float* ebtmax = ktmax + BH * 32;                           // B*L*32
    unsigned int* skipm = (unsigned int*)(ebtmax + (long long)BATCH * L_SEQ * 32); // B*H*32
    float* OUT = EP;                                           // EP dead after ln

    const int M = BATCH * L_SEQ;                               // 4096
    dim3 blk(256);

    cvt6<<<dim3((unsigned)(MD / 1024), 6), blk, 0, stream>>>(
        x, wq, wk, wv, ep_w, wo_w, Xh, wqh, wkh, wvh, eph, woh,
        MD, WN, WN, WN, WN, WN);

    proj_gemm<<<dim3(D_MODEL / 128, M / 128, 4), blk, 0, stream>>>(
        Xh, wqh, wkh, wvh, eph, ep_b, Qh, Kh, Vf, EP, qn, kn);

    ln_rows<<<dim3(M), blk, 0, stream>>>(EP, nullptr, en_g, en_b, nullptr, EFh);

    gemm_bf16<<<dim3(L_SEQ / 128, L_SEQ / 128, BATCH), blk, 0, stream>>>(
        EFh, EFh, nullptr, nullptr, EBh, L_SEQ, D_MODEL,
        (long long)L_SEQ * D_MODEL, (long long)L_SEQ * D_MODEL,
        (long long)L_SEQ * L_SEQ, ebtmax);

    kstats2<<<dim3((unsigned)BH), blk, 0, stream>>>(kn, kmax, ktmax);
    skip_mask<<<dim3(L_SEQ / 64, NUM_HEADS, BATCH), dim3(64), 0, stream>>>(
        ebtmax, qn, kmax, ktmax, skipm, ebmax);

    transpose_v<<<dim3(L_SEQ / 64, NUM_HEADS, BATCH), blk, 0, stream>>>(Vf, Vt);

    attn_mfma<<<dim3(L_SEQ / 64, NUM_HEADS, BATCH), blk, 0, stream>>>(
        Qh, Kh, Vt, EBh, ebmax, qn, kmax, skipm, attn_out, CTXh);

    gemm_bf16<<<dim3(D_MODEL / 128, M / 128, 1), blk, 0, stream>>>(
        CTXh, woh, wo_b, OUT, nullptr, D_MODEL, D_MODEL, 0, 0, 0, nullptr);

    ln_rows<<<dim3(M), blk, 0, stream>>>(OUT, x, ln_g, ln_b, out_final, nullptr);
}

// Round 6
// 735.307 us; speedup vs baseline: 1.2652x; 1.0105x over previous
//
#include <hip/hip_runtime.h>
#include <math.h>

#define D_MODEL 1024
#define NUM_HEADS 16
#define DK 64
#define L_SEQ 2048
#define BATCH 2
#define LN_EPS 1e-5f
#define ENERGY_SCALE 0.1f

typedef __attribute__((ext_vector_type(8))) short short8;
typedef __attribute__((ext_vector_type(4))) float f32x4;
typedef __attribute__((address_space(1))) const unsigned int gas_u32;
typedef __attribute__((address_space(3))) unsigned int las_u32;

__device__ __forceinline__ float waveReduceSum(float v) {
#pragma unroll
    for (int off = 32; off > 0; off >>= 1) v += __shfl_xor(v, off, 64);
    return v;
}

__device__ __forceinline__ unsigned short f2bf(float f) {
    unsigned int u = __float_as_uint(f);
    u += 0x7fff + ((u >> 16) & 1);          // round-to-nearest-even
    return (unsigned short)(u >> 16);
}
__device__ __forceinline__ float bf2f(unsigned short u) {
    return __uint_as_float((unsigned int)u << 16);
}

// ---------------- fp32 -> bf16 convert, 6 matrices in one launch ----------------
__global__ __launch_bounds__(256) void cvt6(
    const float* s0, const float* s1, const float* s2,
    const float* s3, const float* s4, const float* s5,
    unsigned short* d0, unsigned short* d1, unsigned short* d2,
    unsigned short* d3, unsigned short* d4, unsigned short* d5,
    long long n0, long long n1, long long n2, long long n3, long long n4, long long n5)
{
    const float* s; unsigned short* d; long long n;
    switch (blockIdx.y) {
        case 0: s = s0; d = d0; n = n0; break;
        case 1: s = s1; d = d1; n = n1; break;
        case 2: s = s2; d = d2; n = n2; break;
        case 3: s = s3; d = d3; n = n3; break;
        case 4: s = s4; d = d4; n = n4; break;
        default: s = s5; d = d5; n = n5; break;
    }
    long long i = ((long long)blockIdx.x * 256 + threadIdx.x) * 4;
    if (i >= n) return;
    float4 v = *(const float4*)(s + i);
    ushort4 o;
    o.x = f2bf(v.x); o.y = f2bf(v.y); o.z = f2bf(v.z); o.w = f2bf(v.w);
    *(ushort4*)(d + i) = o;
}

// ---------------- bf16 MFMA GEMM with global_load_lds; optional fused
//                  per-(row, 64-col-tile) max epilogue (for EB stats) ----------------
__global__ __launch_bounds__(256) void gemm_bf16(
    const unsigned short* __restrict__ A, const unsigned short* __restrict__ B,
    const float* __restrict__ bias, float* __restrict__ Cf, unsigned short* __restrict__ Ch,
    int N, int K, long long sA, long long sB, long long sC,
    float* __restrict__ ebtmax)
{
    A += (long long)blockIdx.z * sA;
    B += (long long)blockIdx.z * sB;
    __shared__ unsigned short As[128 * 64];
    __shared__ unsigned short Bs[128 * 64];
    const int tid = threadIdx.x;
    const int lane = tid & 63, w = tid >> 6;
    const int quad = lane >> 4, col = lane & 15;
    const int wm = w & 1, wn = w >> 1;
    const int row0 = blockIdx.y * 128, col0 = blockIdx.x * 128;

    const int lr = lane >> 3, lc = lane & 7;
    const int gcs = (lc ^ lr) * 8;

    f32x4 acc[4][4];
#pragma unroll
    for (int mt = 0; mt < 4; mt++)
#pragma unroll
        for (int nt = 0; nt < 4; nt++) acc[mt][nt] = (f32x4){0.f, 0.f, 0.f, 0.f};

    for (int k0 = 0; k0 < K; k0 += 64) {
        __syncthreads();
#pragma unroll
        for (int p = 0; p < 4; p++) {
            const int rb = w * 32 + p * 8;
            __builtin_amdgcn_global_load_lds(
                (gas_u32*)(A + (long long)(row0 + rb + lr) * K + k0 + gcs),
                (las_u32*)(As + rb * 64), 16, 0, 0);
            __builtin_amdgcn_global_load_lds(
                (gas_u32*)(B + (long long)(col0 + rb + lr) * K + k0 + gcs),
                (las_u32*)(Bs + rb * 64), 16, 0, 0);
        }
        __syncthreads();
#pragma unroll
        for (int kc = 0; kc < 2; kc++) {
            const int csw = ((quad + 4 * kc) ^ (col & 7)) * 8;
            short8 af[4], bfr[4];
#pragma unroll
            for (int mt = 0; mt < 4; mt++)
                af[mt] = *(const short8*)(As + (wm * 64 + mt * 16 + col) * 64 + csw);
#pragma unroll
            for (int nt = 0; nt < 4; nt++)
                bfr[nt] = *(const short8*)(Bs + (wn * 64 + nt * 16 + col) * 64 + csw);
#pragma unroll
            for (int mt = 0; mt < 4; mt++)
#pragma unroll
                for (int nt = 0; nt < 4; nt++)
                    acc[mt][nt] = __builtin_amdgcn_mfma_f32_16x16x32_bf16(af[mt], bfr[nt], acc[mt][nt], 0, 0, 0);
        }
    }

#pragma unroll
    for (int mt = 0; mt < 4; mt++)
#pragma unroll
        for (int nt = 0; nt < 4; nt++)
#pragma unroll
            for (int reg = 0; reg < 4; reg++) {
                long long row = row0 + wm * 64 + mt * 16 + quad * 4 + reg;
                int c = col0 + wn * 64 + nt * 16 + col;
                float v = acc[mt][nt][reg];
                if (bias) v += bias[c];
                if (Cf) Cf[blockIdx.z * sC + row * N + c] = v;
                else    Ch[blockIdx.z * sC + row * N + c] = f2bf(v);
            }

    // fused EB per-(row, col-tile) max: each wave's 64 cols = one 64-col tile
    if (ebtmax) {
        const int tcol = blockIdx.x * 2 + wn;
#pragma unroll
        for (int mt = 0; mt < 4; mt++) {
            float mx[4];
#pragma unroll
            for (int reg = 0; reg < 4; reg++) mx[reg] = acc[mt][0][reg];
#pragma unroll
            for (int nt = 1; nt < 4; nt++)
#pragma unroll
                for (int reg = 0; reg < 4; reg++)
                    mx[reg] = fmaxf(mx[reg], acc[mt][nt][reg]);
#pragma unroll
            for (int off = 8; off > 0; off >>= 1)
#pragma unroll
                for (int reg = 0; reg < 4; reg++)
                    mx[reg] = fmaxf(mx[reg], __shfl_xor(mx[reg], off, 64));
            if (col == 0) {
                long long rowg = (long long)blockIdx.z * L_SEQ + row0 + wm * 64 + mt * 16 + quad * 4;
#pragma unroll
                for (int reg = 0; reg < 4; reg++)
                    ebtmax[(rowg + reg) * 32 + tcol] = bf2f(f2bf(mx[reg]));  // bound on rounded values
            }
        }
    }
}

// ---------------- fused projections: Q/K (+row norms), V (direct V^T store), EP ----------------
__global__ __launch_bounds__(256) void proj_gemm(
    const unsigned short* __restrict__ Xh,
    const unsigned short* __restrict__ wqh, const unsigned short* __restrict__ wkh,
    const unsigned short* __restrict__ wvh, const unsigned short* __restrict__ eph,
    const float* __restrict__ ep_b,
    unsigned short* __restrict__ Qh, unsigned short* __restrict__ Kh,
    unsigned short* __restrict__ Vt, float* __restrict__ EP,
    float* __restrict__ qn, float* __restrict__ kn)
{
    const unsigned short* B;
    switch (blockIdx.z) {
        case 0: B = wqh; break;
        case 1: B = wkh; break;
        case 2: B = wvh; break;
        default: B = eph; break;
    }
    __shared__ unsigned short As[128 * 64];
    __shared__ unsigned short Bs[128 * 64];
    const int tid = threadIdx.x;
    const int lane = tid & 63, w = tid >> 6;
    const int quad = lane >> 4, col = lane & 15;
    const int wm = w & 1, wn = w >> 1;
    const int row0 = blockIdx.y * 128, col0 = blockIdx.x * 128;
    const int K = D_MODEL, N = D_MODEL;

    const int lr = lane >> 3, lc = lane & 7;
    const int gcs = (lc ^ lr) * 8;

    f32x4 acc[4][4];
#pragma unroll
    for (int mt = 0; mt < 4; mt++)
#pragma unroll
        for (int nt = 0; nt < 4; nt++) acc[mt][nt] = (f32x4){0.f, 0.f, 0.f, 0.f};

    for (int k0 = 0; k0 < K; k0 += 64) {
        __syncthreads();
#pragma unroll
        for (int p = 0; p < 4; p++) {
            const int rb = w * 32 + p * 8;
            __builtin_amdgcn_global_load_lds(
                (gas_u32*)(Xh + (long long)(row0 + rb + lr) * K + k0 + gcs),
                (las_u32*)(As + rb * 64), 16, 0, 0);
            __builtin_amdgcn_global_load_lds(
                (gas_u32*)(B + (long long)(col0 + rb + lr) * K + k0 + gcs),
                (las_u32*)(Bs + rb * 64), 16, 0, 0);
        }
        __syncthreads();
#pragma unroll
        for (int kc = 0; kc < 2; kc++) {
            const int csw = ((quad + 4 * kc) ^ (col & 7)) * 8;
            short8 af[4], bfr[4];
#pragma unroll
            for (int mt = 0; mt < 4; mt++)
                af[mt] = *(const short8*)(As + (wm * 64 + mt * 16 + col) * 64 + csw);
#pragma unroll
            for (int nt = 0; nt < 4; nt++)
                bfr[nt] = *(const short8*)(Bs + (wn * 64 + nt * 16 + col) * 64 + csw);
#pragma unroll
            for (int mt = 0; mt < 4; mt++)
#pragma unroll
                for (int nt = 0; nt < 4; nt++)
                    acc[mt][nt] = __builtin_amdgcn_mfma_f32_16x16x32_bf16(af[mt], bfr[nt], acc[mt][nt], 0, 0, 0);
        }
    }

    if (blockIdx.z == 2) {
        // V^T fused transpose: 4 quarter-tiles (64x64) through Bs with XOR swizzle,
        // then coalesced short8 stores to Vt[(b,h,d)][l].
        const int b = row0 >> 11;
        const int l0loc = row0 & (L_SEQ - 1);
#pragma unroll
        for (int ch = 0; ch < 2; ch++)
#pragma unroll
            for (int rh = 0; rh < 2; rh++) {
                __syncthreads();        // Bs free (prev quarter readers / K-loop done)
                if (wm == rh && wn == ch) {
#pragma unroll
                    for (int mt = 0; mt < 4; mt++)
#pragma unroll
                        for (int nt = 0; nt < 4; nt++)
#pragma unroll
                            for (int reg = 0; reg < 4; reg++) {
                                int r = mt * 16 + quad * 4 + reg;   // local row (l)
                                int c = nt * 16 + col;              // local col (d)
                                Bs[c * 64 + (r ^ ((c & 7) << 3))] = f2bf(acc[mt][nt][reg]);
                            }
                }
                __syncthreads();
                const int hh = blockIdx.x * 2 + ch;
#pragma unroll
                for (int it = 0; it < 2; it++) {
                    int dd = it * 32 + (tid >> 3);   // 0..63 local d
                    int lcn = (tid & 7) * 8;         // 8 l's
                    short8 v = *(const short8*)(Bs + dd * 64 + (lcn ^ ((dd & 7) << 3)));
                    long long dst = (((long long)(b * NUM_HEADS + hh)) * DK + dd) * L_SEQ
                                    + l0loc + rh * 64 + lcn;
                    *(short8*)(Vt + dst) = v;
                }
            }
        return;
    }

    unsigned short* Hout = (blockIdx.z == 0) ? Qh : Kh;
#pragma unroll
    for (int mt = 0; mt < 4; mt++)
#pragma unroll
        for (int nt = 0; nt < 4; nt++)
#pragma unroll
            for (int reg = 0; reg < 4; reg++) {
                long long row = row0 + wm * 64 + mt * 16 + quad * 4 + reg;
                int c = col0 + wn * 64 + nt * 16 + col;
                float v = acc[mt][nt][reg];
                if (blockIdx.z == 3) EP[row * N + c] = v + ep_b[c];
                else                 Hout[row * N + c] = f2bf(v);
            }

    // fused q/k row-norms: each wave's 64 cols align exactly with one head
    if (blockIdx.z <= 1) {
        float* dst = (blockIdx.z == 0) ? qn : kn;
        const int hh = blockIdx.x * 2 + wn;
#pragma unroll
        for (int mt = 0; mt < 4; mt++) {
            float s2[4];
#pragma unroll
            for (int reg = 0; reg < 4; reg++) s2[reg] = 0.f;
#pragma unroll
            for (int nt = 0; nt < 4; nt++)
#pragma unroll
                for (int reg = 0; reg < 4; reg++)
                    s2[reg] += acc[mt][nt][reg] * acc[mt][nt][reg];
#pragma unroll
            for (int off = 8; off > 0; off >>= 1)
#pragma unroll
                for (int reg = 0; reg < 4; reg++)
                    s2[reg] += __shfl_xor(s2[reg], off, 64);
            if (col == 0) {
                int row = row0 + wm * 64 + mt * 16 + quad * 4;
                int bb = row >> 11, l = row & (L_SEQ - 1);
                float4 o;
                o.x = sqrtf(s2[0]); o.y = sqrtf(s2[1]);
                o.z = sqrtf(s2[2]); o.w = sqrtf(s2[3]);
                *(float4*)(dst + ((long long)(bb * NUM_HEADS + hh)) * L_SEQ + l) = o;
            }
        }
    }
}

// ---------------- LayerNorm rows (float4 vectorized) ----------------
__global__ __launch_bounds__(256) void ln_rows(
    const float* __restrict__ in, const float* __restrict__ res,
    const float* __restrict__ g, const float* __restrict__ bta,
    float* __restrict__ outf, unsigned short* __restrict__ outh)
{
    const long long row = blockIdx.x;
    const float* ip = in + row * D_MODEL;
    const float* rp = res ? res + row * D_MODEL : nullptr;
    const int tid = threadIdx.x;
    const int idx = tid * 4;
    float4 v = *(const float4*)(ip + idx);
    if (rp) {
        float4 r = *(const float4*)(rp + idx);
        v.x += r.x; v.y += r.y; v.z += r.z; v.w += r.w;
    }
    float s = v.x + v.y + v.z + v.w;
    float ss = v.x * v.x + v.y * v.y + v.z * v.z + v.w * v.w;
    __shared__ float sred[4], ssred[4];
    s = waveReduceSum(s); ss = waveReduceSum(ss);
    int wave = tid >> 6, lane = tid & 63;
    if (lane == 0) { sred[wave] = s; ssred[wave] = ss; }
    __syncthreads();
    float ts = sred[0] + sred[1] + sred[2] + sred[3];
    float tss = ssred[0] + ssred[1] + ssred[2] + ssred[3];
    float mu = ts * (1.f / D_MODEL);
    float var = tss * (1.f / D_MODEL) - mu * mu;
    float rs = rsqrtf(var + LN_EPS);
    float4 gg = *(const float4*)(g + idx);
    float4 bb = *(const float4*)(bta + idx);
    if (outf) {
        f32x4 o;
        o[0] = (v.x - mu) * rs * gg.x + bb.x;
        o[1] = (v.y - mu) * rs * gg.y + bb.y;
        o[2] = (v.z - mu) * rs * gg.z + bb.z;
        o[3] = (v.w - mu) * rs * gg.w + bb.w;
        __builtin_nontemporal_store(o, (f32x4*)(outf + row * D_MODEL + idx));
    } else {
        ushort4 o;
        o.x = f2bf((v.x - mu) * rs * gg.x + bb.x);
        o.y = f2bf((v.y - mu) * rs * gg.y + bb.y);
        o.z = f2bf((v.z - mu) * rs * gg.z + bb.z);
        o.w = f2bf((v.w - mu) * rs * gg.w + bb.w);
        *(ushort4*)(outh + row * D_MODEL + idx) = o;
    }
}

// ---------------- skip mask (kstats + ebmax derivation fused in) ----------------
__global__ __launch_bounds__(64) void skip_mask(
    const float* __restrict__ ebtmax, const float* __restrict__ qn,
    const float* __restrict__ kn,
    unsigned int* __restrict__ skipm, float* __restrict__ ebmax,
    float* __restrict__ kmaxg)
{
    const int l0 = blockIdx.x * 64, h = blockIdx.y, b = blockIdx.z;
    const int tid = threadIdx.x;
    const int row = l0 + tid;
    const int bh = b * NUM_HEADS + h;

    // per-tile k-norm maxima from kn (8 KB, L2-resident); lane pair (2t,2t+1) -> tile t
    float ktm_pair;
    {
        const float* p = kn + (long long)bh * L_SEQ + (tid >> 1) * 64 + (tid & 1) * 32;
        float4 a = *(const float4*)(p);
        float m = fmaxf(fmaxf(a.x, a.y), fmaxf(a.z, a.w));
#pragma unroll
        for (int i = 4; i < 32; i += 4) {
            float4 c = *(const float4*)(p + i);
            m = fmaxf(m, fmaxf(fmaxf(c.x, c.y), fmaxf(c.z, c.w)));
        }
        m = fmaxf(m, __shfl_xor(m, 1, 64));
        ktm_pair = m;
    }
    float km = ktm_pair;
#pragma unroll
    for (int off = 2; off < 64; off <<= 1) km = fmaxf(km, __shfl_xor(km, off, 64));
    if (blockIdx.x == 0 && tid == 0) kmaxg[bh] = km;

    const float* ebt = ebtmax + ((long long)b * L_SEQ + row) * 32;
    float ebr[32];
#pragma unroll
    for (int t = 0; t < 32; t++) ebr[t] = ebt[t];
    float mx = ebr[0];
#pragma unroll
    for (int t = 1; t < 32; t++) mx = fmaxf(mx, ebr[t]);
    if (blockIdx.y == 0) ebmax[(long long)b * L_SEQ + row] = mx;

    float q = qn[(long long)bh * L_SEQ + row];
    float Mh = ENERGY_SCALE * mx + q * km * 0.125f + 0.02f;
    unsigned int m = 0;
#pragma unroll
    for (int t = 0; t < 32; t++) {
        float kt = __shfl(ktm_pair, 2 * t, 64);
        float ub = ENERGY_SCALE * ebr[t] + q * kt * 0.125f;
        unsigned long long bal = __ballot(ub < Mh - 45.0f);
        if (bal == ~0ull) m |= (1u << t);
    }
    if (tid == 0) skipm[bh * 32 + blockIdx.x] = m;
}

// ---------------- MFMA attention: async double-buffered K staging, single-barrier
//                  pass 1, overlapped V staging + deferred p stores in pass 2;
//                  EB consumed as bf16; tile-skip via precomputed mask;
//                  nontemporal stores for attn_out (never re-read) ----------------
__global__ __launch_bounds__(256) void attn_mfma(
    const unsigned short* __restrict__ Qh, const unsigned short* __restrict__ Kh,
    const unsigned short* __restrict__ Vt, const unsigned short* __restrict__ EBh,
    const float* __restrict__ ebmax, const float* __restrict__ qn,
    const float* __restrict__ kmax, const unsigned int* __restrict__ skipm,
    float* __restrict__ attn_out, unsigned short* __restrict__ CTXh)
{
    __shared__ unsigned short Ks[2][64 * 64];   // K tile double buffer (16 KB)
    __shared__ unsigned short Vts[64 * 64];     // V tile single buffer  (8 KB)
    __shared__ unsigned short Ps[4 * 16 * 72];  // per-wave P scratch    (9 KB)

    const int tid = threadIdx.x;
    const int lane = tid & 63, w = tid >> 6;
    const int quad = lane >> 4, col = lane & 15;
    const int l0 = blockIdx.x * 64;
    const int h = blockIdx.y, b = blockIdx.z;

    const unsigned int sm = skipm[(b * NUM_HEADS + h) * 32 + blockIdx.x];

    const unsigned short* kbase = Kh + ((long long)b * L_SEQ) * D_MODEL + h * DK;
    const unsigned short* vbase = Vt + ((long long)(b * NUM_HEADS + h)) * DK * L_SEQ;

    const int lr = lane >> 3, lc = lane & 7;
    const int gsw = (lc ^ lr) * 8;       // swizzled global chunk offset (shorts)

    auto nxt = [&](int t) -> int {
        unsigned int rem = ~sm;
        if (t >= 0) rem &= (t >= 31) ? 0u : (0xFFFFFFFFu << (t + 1));
        return rem ? (int)__builtin_ctz(rem) : -1;
    };
    const int t0 = nxt(-1);

    // ---- prologue: issue first K stage ASAP (async DMA) ----
    if (t0 >= 0) {
#pragma unroll
        for (int p = 0; p < 2; p++) {
            const int rb = w * 8 + p * 32;
            __builtin_amdgcn_global_load_lds(
                (gas_u32*)(kbase + (long long)(t0 * 64 + rb + lr) * D_MODEL + gsw),
                (las_u32*)(&Ks[0][rb * 64]), 16, 0, 0);
        }
    }

    // ---- coalesced zero-fill for skipped tiles (nontemporal, fire-and-forget) ----
    {
        float* zbase = attn_out + (((long long)(b * NUM_HEADS + h)) * L_SEQ + l0) * L_SEQ;
        const int zc = (tid & 15) * 4;
        const int zr = tid >> 4;
        const f32x4 zv = {0.f, 0.f, 0.f, 0.f};
        for (int t = 0; t < 32; t++) {
            if (!(sm & (1u << t))) continue;
            float* tb = zbase + t * 64 + zc;
#pragma unroll
            for (int rr = 0; rr < 4; rr++)
                __builtin_nontemporal_store(zv, (f32x4*)(tb + (long long)(rr * 16 + zr) * L_SEQ));
        }
    }

    short8 aq[2];
    {
        const unsigned short* qrow = Qh + ((long long)b * L_SEQ + l0 + w * 16 + col) * D_MODEL + h * DK;
        aq[0] = *(const short8*)(qrow + quad * 8);
        aq[1] = *(const short8*)(qrow + 32 + quad * 8);
    }

    float Mhat[4];
    {
        const float km = kmax[b * NUM_HEADS + h];
#pragma unroll
        for (int reg = 0; reg < 4; reg++) {
            int row = l0 + w * 16 + quad * 4 + reg;
            float qb = qn[((long long)(b * NUM_HEADS + h)) * L_SEQ + row];
            Mhat[reg] = ENERGY_SCALE * ebmax[(long long)b * L_SEQ + row] +
                        qb * km * 0.125f + 0.02f;
        }
    }

    const unsigned short* ebp = EBh + ((long long)b * L_SEQ + l0 + w * 16 + quad * 4) * L_SEQ + col;

    __syncthreads();   // drains prologue stage (vmcnt) + joins waves

    // ---- pass 1: rowS over active tiles, ONE barrier per tile, K prefetched ----
    float rowSacc[4] = {0.f, 0.f, 0.f, 0.f};
    int cur = 0;
    for (int t = t0; t >= 0; ) {
        const int tn = nxt(t);
        if (tn >= 0) {
#pragma unroll
            for (int p = 0; p < 2; p++) {
                const int rb = w * 8 + p * 32;
                __builtin_amdgcn_global_load_lds(
                    (gas_u32*)(kbase + (long long)(tn * 64 + rb + lr) * D_MODEL + gsw),
                    (las_u32*)(&Ks[cur ^ 1][rb * 64]), 16, 0, 0);
            }
        }
        const int m0 = t * 64;

        f32x4 acc[4];
#pragma unroll
        for (int nt = 0; nt < 4; nt++) acc[nt] = (f32x4){0.f, 0.f, 0.f, 0.f};
        __builtin_amdgcn_s_setprio(1);
#pragma unroll
        for (int nt = 0; nt < 4; nt++)
#pragma unroll
            for (int kc = 0; kc < 2; kc++) {
                short8 bk = *(const short8*)(&Ks[cur][((nt * 16 + col) << 6) +
                                                     (((quad + 4 * kc) ^ (col & 7)) << 3)]);
                acc[nt] = __builtin_amdgcn_mfma_f32_16x16x32_bf16(aq[kc], bk, acc[nt], 0, 0, 0);
            }
        __builtin_amdgcn_s_setprio(0);
#pragma unroll
        for (int nt = 0; nt < 4; nt++)
#pragma unroll
            for (int reg = 0; reg < 4; reg++) {
                float e = bf2f(ebp[(long long)reg * L_SEQ + m0 + nt * 16]);
                float s = acc[nt][reg] * 0.125f + ENERGY_SCALE * e;
                rowSacc[reg] += __expf(s - Mhat[reg]);
            }
        __syncthreads();   // next K landed; Ks[cur] free for overwrite next iter
        cur ^= 1;
        t = tn;
    }

    float invS[4];
#pragma unroll
    for (int reg = 0; reg < 4; reg++) {
        float v = rowSacc[reg];
#pragma unroll
        for (int off = 8; off > 0; off >>= 1) v += __shfl_xor(v, off, 64);
        invS[reg] = 1.f / v;
    }

    // ---- pass 2 prologue: restage first K tile ----
    cur = 0;
    if (t0 >= 0) {
#pragma unroll
        for (int p = 0; p < 2; p++) {
            const int rb = w * 8 + p * 32;
            __builtin_amdgcn_global_load_lds(
                (gas_u32*)(kbase + (long long)(t0 * 64 + rb + lr) * D_MODEL + gsw),
                (las_u32*)(&Ks[0][rb * 64]), 16, 0, 0);
        }
    }
    __syncthreads();

    // ---- pass 2: p writes + ctx = P V; V staged async under QK, p stores after barrier ----
    f32x4 ctx[4];
#pragma unroll
    for (int nt = 0; nt < 4; nt++) ctx[nt] = (f32x4){0.f, 0.f, 0.f, 0.f};

    unsigned short* Psw = Ps + w * 16 * 72;
    float* aob = attn_out + (((long long)(b * NUM_HEADS + h)) * L_SEQ + l0 + w * 16 + quad * 4) * L_SEQ + col;

    for (int t = t0; t >= 0; ) {
        const int tn = nxt(t);
        const int m0 = t * 64;

        // stage V(t) — hidden under the QK phase below
#pragma unroll
        for (int p = 0; p < 2; p++) {
            const int rb = w * 8 + p * 32;
            __builtin_amdgcn_global_load_lds(
                (gas_u32*)(vbase + (long long)(rb + lr) * L_SEQ + m0 + gsw),
                (las_u32*)(&Vts[rb * 64]), 16, 0, 0);
        }
        // prefetch next K tile
        if (tn >= 0) {
#pragma unroll
            for (int p = 0; p < 2; p++) {
                const int rb = w * 8 + p * 32;
                __builtin_amdgcn_global_load_lds(
                    (gas_u32*)(kbase + (long long)(tn * 64 + rb + lr) * D_MODEL + gsw),
                    (las_u32*)(&Ks[cur ^ 1][rb * 64]), 16, 0, 0);
            }
        }

        f32x4 acc[4];
#pragma unroll
        for (int nt = 0; nt < 4; nt++) acc[nt] = (f32x4){0.f, 0.f, 0.f, 0.f};
        __builtin_amdgcn_s_setprio(1);
#pragma unroll
        for (int nt = 0; nt < 4; nt++)
#pragma unroll
            for (int kc = 0; kc < 2; kc++) {
                short8 bk = *(const short8*)(&Ks[cur][((nt * 16 + col) << 6) +
                                                     (((quad + 4 * kc) ^ (col & 7)) << 3)]);
                acc[nt] = __builtin_amdgcn_mfma_f32_16x16x32_bf16(aq[kc], bk, acc[nt], 0, 0, 0);
            }
        __builtin_amdgcn_s_setprio(0);

        // transform scores -> normalized p in-place; write P to per-wave LDS scratch
#pragma unroll
        for (int nt = 0; nt < 4; nt++)
#pragma unroll
            for (int reg = 0; reg < 4; reg++) {
                float e = bf2f(ebp[(long long)reg * L_SEQ + m0 + nt * 16]);
                float s = acc[nt][reg] * 0.125f + ENERGY_SCALE * e;
                float p = __expf(s - Mhat[reg]) * invS[reg];
                acc[nt][reg] = p;
                Psw[(quad * 4 + reg) * 72 + nt * 16 + col] = f2bf(p);
            }
        __syncthreads();   // V tile landed (and next K issued early)

        // global p stores issued now (nontemporal) — drain during the PV phase
#pragma unroll
        for (int nt = 0; nt < 4; nt++)
#pragma unroll
            for (int reg = 0; reg < 4; reg++)
                __builtin_nontemporal_store(acc[nt][reg],
                    aob + (long long)reg * L_SEQ + m0 + nt * 16);

        short8 ap[2];
#pragma unroll
        for (int kc = 0; kc < 2; kc++)
            ap[kc] = *(const short8*)(Psw + col * 72 + quad * 8 + kc * 32);
        __builtin_amdgcn_s_setprio(1);
#pragma unroll
        for (int nt = 0; nt < 4; nt++)
#pragma unroll
            for (int kc = 0; kc < 2; kc++) {
                short8 bv = *(const short8*)(&Vts[((nt * 16 + col) << 6) +
                                                  (((quad + 4 * kc) ^ (col & 7)) << 3)]);
                ctx[nt] = __builtin_amdgcn_mfma_f32_16x16x32_bf16(ap[kc], bv, ctx[nt], 0, 0, 0);
            }
        __builtin_amdgcn_s_setprio(0);
        __syncthreads();   // protect Vts (and Ps) against next-iter overwrite
        cur ^= 1;
        t = tn;
    }

#pragma unroll
    for (int nt = 0; nt < 4; nt++)
#pragma unroll
        for (int reg = 0; reg < 4; reg++)
            CTXh[((long long)b * L_SEQ + l0 + w * 16 + quad * 4 + reg) * D_MODEL + h * DK + nt * 16 + col] =
                f2bf(ctx[nt][reg]);
}

extern "C" void kernel_launch(void* const* d_in, const int* in_sizes, int n_in,
                              void* d_out, int out_size, void* d_ws, size_t ws_size,
                              hipStream_t stream) {
    const float* x    = (const float*)d_in[0];
    const float* wq   = (const float*)d_in[1];
    const float* wk   = (const float*)d_in[2];
    const float* wv   = (const float*)d_in[3];
    const float* wo_w = (const float*)d_in[4];
    const float* wo_b = (const float*)d_in[5];
    const float* ep_w = (const float*)d_in[6];
    const float* ep_b = (const float*)d_in[7];
    const float* en_g = (const float*)d_in[8];
    const float* en_b = (const float*)d_in[9];
    const float* ln_g = (const float*)d_in[10];
    const float* ln_b = (const float*)d_in[11];

    float* out_final = (float*)d_out;
    float* attn_out  = out_final + (long long)BATCH * L_SEQ * D_MODEL;

    const long long MD = (long long)BATCH * L_SEQ * D_MODEL;   // 4,194,304
    const long long WN = (long long)D_MODEL * D_MODEL;         // 1,048,576
    const long long BH = (long long)BATCH * NUM_HEADS;
    const long long LL = (long long)BATCH * L_SEQ * L_SEQ;     // 8,388,608

    unsigned short* EBh = (unsigned short*)d_ws;               // [B,L,L] bf16
    float* EP = (float*)(EBh + LL);                            // MD fp32 (also OUT)
    unsigned short* Xh   = (unsigned short*)(EP + MD);
    unsigned short* Qh   = Xh + MD;
    unsigned short* Kh   = Qh + MD;
    unsigned short* Vfu  = Kh + MD;                            // (unused slot, kept for layout)
    unsigned short* Vt   = Vfu + MD;
    unsigned short* EFh  = Vt + MD;
    unsigned short* CTXh = EFh + MD;
    unsigned short* wqh  = CTXh + MD;
    unsigned short* wkh  = wqh + WN;
    unsigned short* wvh  = wkh + WN;
    unsigned short* eph  = wvh + WN;
    unsigned short* woh  = eph + WN;
    float* ebmax  = (float*)(woh + WN);                        // B*L
    float* qn     = ebmax + (long long)BATCH * L_SEQ;          // B*H*L
    float* kn     = qn + BH * L_SEQ;                           // B*H*L
    float* kmax   = kn + BH * L_SEQ;                           // B*H
    float* ktmaxu = kmax + BH;                                 // (unused slot, kept for layout)
    float* ebtmax = ktmaxu + BH * 32;                          // B*L*32
    unsigned int* skipm = (unsigned int*)(ebtmax + (long long)BATCH * L_SEQ * 32); // B*H*32
    float* OUT = EP;                                           // EP dead after ln

    const int M = BATCH * L_SEQ;                               // 4096
    dim3 blk(256);

    cvt6<<<dim3((unsigned)(MD / 1024), 6), blk, 0, stream>>>(
        x, wq, wk, wv, ep_w, wo_w, Xh, wqh, wkh, wvh, eph, woh,
        MD, WN, WN, WN, WN, WN);

    proj_gemm<<<dim3(D_MODEL / 128, M / 128, 4), blk, 0, stream>>>(
        Xh, wqh, wkh, wvh, eph, ep_b, Qh, Kh, Vt, EP, qn, kn);

    ln_rows<<<dim3(M), blk, 0, stream>>>(EP, nullptr, en_g, en_b, nullptr, EFh);

    gemm_bf16<<<dim3(L_SEQ / 128, L_SEQ / 128, BATCH), blk, 0, stream>>>(
        EFh, EFh, nullptr, nullptr, EBh, L_SEQ, D_MODEL,
        (long long)L_SEQ * D_MODEL, (long long)L_SEQ * D_MODEL,
        (long long)L_SEQ * L_SEQ, ebtmax);

    skip_mask<<<dim3(L_SEQ / 64, NUM_HEADS, BATCH), dim3(64), 0, stream>>>(
        ebtmax, qn, kn, skipm, ebmax, kmax);

    attn_mfma<<<dim3(L_SEQ / 64, NUM_HEADS, BATCH), blk, 0, stream>>>(
        Qh, Kh, Vt, EBh, ebmax, qn, kmax, skipm, attn_out, CTXh);

    gemm_bf16<<<dim3(D_MODEL / 128, M / 128, 1), blk, 0, stream>>>(
        CTXh, woh, wo_b, OUT, nullptr, D_MODEL, D_MODEL, 0, 0, 0, nullptr);

    ln_rows<<<dim3(M), blk, 0, stream>>>(OUT, x, ln_g, ln_b, out_final, nullptr);
}